// Round 4
// baseline (860.483 us; speedup 1.0000x reference)
//
#include <hip/hip_runtime.h>

#define NN 100000
#define EE 1600000
#define CH 128
#define NG 512
#define OC 64

// CSR bucketing: 128 nodes/bucket
#define BSH 7
#define NB 782          // ceil(NN/128)
#define BCAP 3072       // mean 2048 + 22 sigma

// workspace element offsets (4-byte units)
#define O_DINV   0
#define O_DEG    100096
#define O_ROWS   200128
#define O_BCNT   300160
#define O_PART   400192
#define O_OFFS   400320
#define O_CSR    400448
#define O_HS     2000448   // bf16 Hs: NN*CH ushorts = 3.2M floats used
#define O_STG    5200448   // bucket staging: NB*BCAP words = 2.4M
#define O_A1     14800448
#define O_START  27600448
#define O_POOL   27601024
#define O_G1     27666560

static __device__ __forceinline__ unsigned short f2bf(float x) {
  unsigned u = __float_as_uint(x);
  return (unsigned short)((u + 0x7FFFu + ((u >> 16) & 1u)) >> 16);  // RNE
}
static __device__ __forceinline__ unsigned pack2(float a, float b) {
  return (unsigned)f2bf(a) | ((unsigned)f2bf(b) << 16);
}
static __device__ __forceinline__ float bflo(unsigned v) {
  return __uint_as_float(v << 16);
}
static __device__ __forceinline__ float bfhi(unsigned v) {
  return __uint_as_float(v & 0xFFFF0000u);
}

// Phase A: count degrees + scatter edges into 128-node buckets.
// staged word = src | (dst&127)<<17  (src < 2^17, local dst 7 bits)
__global__ void k_bucket(const int* __restrict__ src, const int* __restrict__ dst,
                         int* __restrict__ deg, int* __restrict__ bcnt,
                         unsigned* __restrict__ staging) {
  int e = blockIdx.x * 256 + threadIdx.x;
  if (e >= EE) return;
  int d = dst[e];
  atomicAdd(&deg[d], 1);
  int b = d >> BSH;
  int pos = atomicAdd(&bcnt[b], 1);
  staging[(size_t)b * BCAP + pos] = (unsigned)src[e] | ((unsigned)(d & 127) << 17);
}

// Phase B: one block per bucket, build CSR segment in LDS, stream out coalesced.
__global__ __launch_bounds__(256) void k_build(const unsigned* __restrict__ staging,
                                               const int* __restrict__ bcnt,
                                               const int* __restrict__ rows,
                                               int* __restrict__ csr) {
  __shared__ int loff[129];
  __shared__ int lcur[128];
  __shared__ int lcsr[BCAP];
  int b = blockIdx.x;
  int t = threadIdx.x;
  int nbase = b << BSH;
  int ncount = min(128, NN - nbase);
  int ebase = rows[nbase];
  if (t <= ncount) loff[t] = rows[nbase + t] - ebase;
  if (t < 128) lcur[t] = 0;
  __syncthreads();
  int cnt = bcnt[b];
  for (int e = t; e < cnt; e += 256) {
    unsigned w = staging[(size_t)b * BCAP + e];
    int ld = w >> 17;
    int s = (int)(w & 0x1FFFFu);
    int p = atomicAdd(&lcur[ld], 1);
    lcsr[loff[ld] + p] = s;
  }
  __syncthreads();
  for (int e = t; e < cnt; e += 256) csr[ebase + e] = lcsr[e];
}

__global__ void k_dinv(const int* __restrict__ deg, float* __restrict__ dinv) {
  int i = blockIdx.x * 256 + threadIdx.x;
  if (i < NN) dinv[i] = rsqrtf((float)(deg[i] + 1));  // +1 self-loop
}

__global__ __launch_bounds__(1024) void k_scan_block(const int* __restrict__ deg,
                                                     int* __restrict__ rows,
                                                     int* __restrict__ part) {
  __shared__ int s[1024];
  int t = threadIdx.x;
  int gid = blockIdx.x * 1024 + t;
  int v = (gid < NN) ? deg[gid] : 0;
  s[t] = v;
  __syncthreads();
  for (int off = 1; off < 1024; off <<= 1) {
    int u = (t >= off) ? s[t - off] : 0;
    __syncthreads();
    if (t >= off) s[t] += u;
    __syncthreads();
  }
  if (gid < NN) rows[gid] = s[t] - v;       // exclusive
  if (t == 1023) part[blockIdx.x] = s[t];   // block total
}

__global__ void k_scan_part(const int* __restrict__ part, int* __restrict__ offs) {
  __shared__ int s[128];
  int t = threadIdx.x;
  int v = (t < 98) ? part[t] : 0;
  s[t] = v;
  __syncthreads();
  for (int off = 1; off < 128; off <<= 1) {
    int u = (t >= off) ? s[t - off] : 0;
    __syncthreads();
    if (t >= off) s[t] += u;
    __syncthreads();
  }
  if (t < 98) offs[t] = s[t] - v;
}

__global__ void k_scan_add(int* __restrict__ rows, const int* __restrict__ offs) {
  int i = blockIdx.x * 256 + threadIdx.x;
  if (i < NN) rows[i] += offs[i >> 10];
  if (i == 0) rows[NN] = EE;
}

// Hs(bf16) = diag(dinv) * (X @ W).  64-row tile, 256 threads, 4x8 register tile.
__global__ __launch_bounds__(256) void k_gemm_scale(
    const float* __restrict__ X, const float* __restrict__ W,
    const float* __restrict__ dinv, unsigned short* __restrict__ Hs) {
  __shared__ float Xs[64][36];
  __shared__ float Ws[32][128];
  const int t = threadIdx.x;
  const int tx = t & 15;
  const int ty = t >> 4;
  const int row0 = blockIdx.x * 64;
  float acc[4][8];
#pragma unroll
  for (int i = 0; i < 4; ++i)
#pragma unroll
    for (int j = 0; j < 8; ++j) acc[i][j] = 0.f;

  const int lr = t >> 2;
  const int lk = (t & 3) * 8;
  const int wk = t >> 5;
  const int wc = (t & 31) * 4;

  for (int kc = 0; kc < 128; kc += 32) {
    if (row0 + lr < NN) {
      const float* xp = X + (size_t)(row0 + lr) * CH + kc + lk;
      *(float4*)&Xs[lr][lk] = *(const float4*)xp;
      *(float4*)&Xs[lr][lk + 4] = *(const float4*)(xp + 4);
    } else {
      float4 z = {0.f, 0.f, 0.f, 0.f};
      *(float4*)&Xs[lr][lk] = z;
      *(float4*)&Xs[lr][lk + 4] = z;
    }
#pragma unroll
    for (int i = 0; i < 4; ++i)
      *(float4*)&Ws[wk + 8 * i][wc] =
          *(const float4*)(W + (size_t)(kc + wk + 8 * i) * CH + wc);
    __syncthreads();
#pragma unroll
    for (int k = 0; k < 32; ++k) {
      float4 w0 = *(float4*)&Ws[k][tx * 8];
      float4 w1 = *(float4*)&Ws[k][tx * 8 + 4];
#pragma unroll
      for (int i = 0; i < 4; ++i) {
        float xv = Xs[ty * 4 + i][k];
        acc[i][0] += xv * w0.x; acc[i][1] += xv * w0.y;
        acc[i][2] += xv * w0.z; acc[i][3] += xv * w0.w;
        acc[i][4] += xv * w1.x; acc[i][5] += xv * w1.y;
        acc[i][6] += xv * w1.z; acc[i][7] += xv * w1.w;
      }
    }
    __syncthreads();
  }
#pragma unroll
  for (int i = 0; i < 4; ++i) {
    int r = row0 + ty * 4 + i;
    if (r < NN) {
      float d = dinv[r];
      uint4 u;
      u.x = pack2(d * acc[i][0], d * acc[i][1]);
      u.y = pack2(d * acc[i][2], d * acc[i][3]);
      u.z = pack2(d * acc[i][4], d * acc[i][5]);
      u.w = pack2(d * acc[i][6], d * acc[i][7]);
      *(uint4*)&Hs[(size_t)r * CH + tx * 8] = u;
    }
  }
}

// out[i] = relu(dinv[i]*(Hs[i] + sum_{e:dst=i} Hs[csr[e]]) + b). One wave per node.
__global__ __launch_bounds__(256) void k_aggregate(
    const unsigned* __restrict__ H, const int* __restrict__ rows,
    const int* __restrict__ csr, const float* __restrict__ dinv,
    const float* __restrict__ bias, float* __restrict__ out) {
  int node = blockIdx.x * 4 + (threadIdx.x >> 6);
  int lane = threadIdx.x & 63;
  if (node >= NN) return;
  unsigned sv = H[(size_t)node * 64 + lane];  // self-loop term
  float ax = bflo(sv), ay = bfhi(sv);
  int e = rows[node], e1 = rows[node + 1];
  for (; e + 4 <= e1; e += 4) {
    int j0 = csr[e], j1 = csr[e + 1], j2 = csr[e + 2], j3 = csr[e + 3];
    unsigned v0 = H[(size_t)j0 * 64 + lane];
    unsigned v1 = H[(size_t)j1 * 64 + lane];
    unsigned v2 = H[(size_t)j2 * 64 + lane];
    unsigned v3 = H[(size_t)j3 * 64 + lane];
    ax += bflo(v0) + bflo(v1) + bflo(v2) + bflo(v3);
    ay += bfhi(v0) + bfhi(v1) + bfhi(v2) + bfhi(v3);
  }
  for (; e < e1; ++e) {
    unsigned v = H[(size_t)csr[e] * 64 + lane];
    ax += bflo(v);
    ay += bfhi(v);
  }
  float d = dinv[node];
  float bx = bias[2 * lane], by = bias[2 * lane + 1];
  float2 o;
  o.x = fmaxf(fmaf(d, ax, bx), 0.f);
  o.y = fmaxf(fmaf(d, ay, by), 0.f);
  ((float2*)out)[(size_t)node * 64 + lane] = o;
}

// batch is sorted: graph g occupies nodes [start[g], start[g+1]).
__global__ void k_starts(const int* __restrict__ batch, int* __restrict__ start) {
  int i = blockIdx.x * 256 + threadIdx.x;
  if (i >= NN) return;
  int b = batch[i];
  int prev = (i == 0) ? -1 : batch[i - 1];
  for (int g = prev + 1; g <= b; ++g) start[g] = i;
  if (i == NN - 1)
    for (int g = b + 1; g <= NG; ++g) start[g] = NN;
}

// one block (2 waves) per graph: segmented mean, no atomics.
__global__ __launch_bounds__(256) void k_pool_mean(
    const float* __restrict__ A, const int* __restrict__ start,
    float* __restrict__ pooled) {
  __shared__ float part[128];
  int g = blockIdx.x;
  int c = threadIdx.x & 127;
  int half = threadIdx.x >> 7;
  int s0 = start[g], s1 = start[g + 1];
  float sum = 0.f;
  for (int i = s0 + half; i < s1; i += 2)
    sum += A[(size_t)i * CH + c];
  if (half) part[c] = sum;
  __syncthreads();
  if (!half) {
    sum += part[c];
    float n = fmaxf((float)(s1 - s0), 1.0f);
    pooled[(size_t)g * CH + c] = sum / n;
  }
}

__global__ void k_head1(const float* __restrict__ pooled,
                        const float* __restrict__ W3, const float* __restrict__ b3,
                        float* __restrict__ g1) {
  __shared__ float row[128];
  int g = blockIdx.x, c = threadIdx.x;
  row[c] = pooled[(size_t)g * CH + c];
  __syncthreads();
  float acc = b3[c];
  for (int k = 0; k < 128; ++k) acc += row[k] * W3[(size_t)k * CH + c];
  g1[(size_t)g * CH + c] = fmaxf(acc, 0.f);
}

__global__ void k_head2(const float* __restrict__ g1, const float* __restrict__ W4,
                        const float* __restrict__ b4, float* __restrict__ out) {
  __shared__ float row[128];
  int g = blockIdx.x, c = threadIdx.x;  // 64 threads
  row[c] = g1[(size_t)g * CH + c];
  row[c + 64] = g1[(size_t)g * CH + c + 64];
  __syncthreads();
  float acc = b4[c];
  for (int k = 0; k < 128; ++k) acc += row[k] * W4[(size_t)k * OC + c];
  out[(size_t)g * OC + c] = acc;
}

extern "C" void kernel_launch(void* const* d_in, const int* in_sizes, int n_in,
                              void* d_out, int out_size, void* d_ws, size_t ws_size,
                              hipStream_t stream) {
  const float* X   = (const float*)d_in[0];
  const int* ei    = (const int*)d_in[1];
  const int* batch = (const int*)d_in[2];
  const float* W1  = (const float*)d_in[3];
  const float* b1  = (const float*)d_in[4];
  const float* W2  = (const float*)d_in[5];
  const float* b2  = (const float*)d_in[6];
  const float* W3  = (const float*)d_in[7];
  const float* b3  = (const float*)d_in[8];
  const float* W4  = (const float*)d_in[9];
  const float* b4  = (const float*)d_in[10];
  float* out = (float*)d_out;
  float* ws = (float*)d_ws;

  const int* src = ei;        // edge_index[0]
  const int* dst = ei + EE;   // edge_index[1]

  float* dinv = ws + O_DINV;
  int* deg    = (int*)(ws + O_DEG);
  int* rows   = (int*)(ws + O_ROWS);
  int* bcnt   = (int*)(ws + O_BCNT);
  int* part   = (int*)(ws + O_PART);
  int* offs   = (int*)(ws + O_OFFS);
  int* csr    = (int*)(ws + O_CSR);
  unsigned short* Hs = (unsigned short*)(ws + O_HS);
  unsigned* stg = (unsigned*)(ws + O_STG);
  float* A1   = ws + O_A1;
  int* start  = (int*)(ws + O_START);
  float* pool = ws + O_POOL;
  float* g1   = ws + O_G1;

  hipMemsetAsync(deg, 0, NN * sizeof(int), stream);
  hipMemsetAsync(bcnt, 0, NB * sizeof(int), stream);

  k_bucket<<<(EE + 255) / 256, 256, 0, stream>>>(src, dst, deg, bcnt, stg);
  k_dinv<<<(NN + 255) / 256, 256, 0, stream>>>(deg, dinv);
  k_scan_block<<<98, 1024, 0, stream>>>(deg, rows, part);
  k_scan_part<<<1, 128, 0, stream>>>(part, offs);
  k_scan_add<<<(NN + 255) / 256, 256, 0, stream>>>(rows, offs);
  k_build<<<NB, 256, 0, stream>>>(stg, bcnt, rows, csr);
  k_starts<<<(NN + 255) / 256, 256, 0, stream>>>(batch, start);

  // layer 1
  k_gemm_scale<<<(NN + 63) / 64, 256, 0, stream>>>(X, W1, dinv, Hs);
  k_aggregate<<<(NN + 3) / 4, 256, 0, stream>>>((const unsigned*)Hs, rows, csr, dinv, b1, A1);
  // layer 2
  k_gemm_scale<<<(NN + 63) / 64, 256, 0, stream>>>(A1, W2, dinv, Hs);
  k_aggregate<<<(NN + 3) / 4, 256, 0, stream>>>((const unsigned*)Hs, rows, csr, dinv, b2, A1);

  k_pool_mean<<<NG, 256, 0, stream>>>(A1, start, pool);
  k_head1<<<NG, 128, 0, stream>>>(pool, W3, b3, g1);
  k_head2<<<NG, 64, 0, stream>>>(g1, W4, b4, out);
}

// Round 5
// 570.969 us; speedup vs baseline: 1.5071x; 1.5071x over previous
//
#include <hip/hip_runtime.h>

#define NN 100000
#define EE 1600000
#define CH 128
#define NG 512
#define OC 64

// workspace element offsets (4-byte units)
#define O_DINV   0
#define O_DEG    100096
#define O_ROWS   200128
#define O_CURS   300160
#define O_PART   400192
#define O_OFFS   400320
#define O_CSR    400448
#define O_HS     2000448   // bf16 Hs: NN*CH ushorts = 3.2M floats used
#define O_A1     14800448
#define O_START  27600448
#define O_POOL   27601024
#define O_G1     27666560

static __device__ __forceinline__ unsigned short f2bf(float x) {
  unsigned u = __float_as_uint(x);
  return (unsigned short)((u + 0x7FFFu + ((u >> 16) & 1u)) >> 16);  // RNE
}
static __device__ __forceinline__ unsigned pack2(float a, float b) {
  return (unsigned)f2bf(a) | ((unsigned)f2bf(b) << 16);
}
static __device__ __forceinline__ float bflo(unsigned v) {
  return __uint_as_float(v << 16);
}
static __device__ __forceinline__ float bfhi(unsigned v) {
  return __uint_as_float(v & 0xFFFF0000u);
}

__global__ void k_deg(const int* __restrict__ dst, int* __restrict__ deg) {
  int e = blockIdx.x * 256 + threadIdx.x;
  if (e < EE) atomicAdd(&deg[dst[e]], 1);
}

__global__ void k_dinv(const int* __restrict__ deg, float* __restrict__ dinv) {
  int i = blockIdx.x * 256 + threadIdx.x;
  if (i < NN) dinv[i] = rsqrtf((float)(deg[i] + 1));  // +1 self-loop
}

__global__ __launch_bounds__(1024) void k_scan_block(const int* __restrict__ deg,
                                                     int* __restrict__ rows,
                                                     int* __restrict__ part) {
  __shared__ int s[1024];
  int t = threadIdx.x;
  int gid = blockIdx.x * 1024 + t;
  int v = (gid < NN) ? deg[gid] : 0;
  s[t] = v;
  __syncthreads();
  for (int off = 1; off < 1024; off <<= 1) {
    int u = (t >= off) ? s[t - off] : 0;
    __syncthreads();
    if (t >= off) s[t] += u;
    __syncthreads();
  }
  if (gid < NN) rows[gid] = s[t] - v;       // exclusive
  if (t == 1023) part[blockIdx.x] = s[t];   // block total
}

__global__ void k_scan_part(const int* __restrict__ part, int* __restrict__ offs) {
  __shared__ int s[128];
  int t = threadIdx.x;
  int v = (t < 98) ? part[t] : 0;
  s[t] = v;
  __syncthreads();
  for (int off = 1; off < 128; off <<= 1) {
    int u = (t >= off) ? s[t - off] : 0;
    __syncthreads();
    if (t >= off) s[t] += u;
    __syncthreads();
  }
  if (t < 98) offs[t] = s[t] - v;
}

__global__ void k_scan_add(int* __restrict__ rows, const int* __restrict__ offs) {
  int i = blockIdx.x * 256 + threadIdx.x;
  if (i < NN) rows[i] += offs[i >> 10];
  if (i == 0) rows[NN] = EE;
}

__global__ void k_fill(const int* __restrict__ src, const int* __restrict__ dst,
                       const int* __restrict__ rows, int* __restrict__ curs,
                       int* __restrict__ csr) {
  int e = blockIdx.x * 256 + threadIdx.x;
  if (e < EE) {
    int d = dst[e];
    int pos = atomicAdd(&curs[d], 1);
    csr[rows[d] + pos] = src[e];
  }
}

// Hs(bf16) = diag(dinv) * (X @ W).  64-row tile, 256 threads, 4x8 register tile.
__global__ __launch_bounds__(256) void k_gemm_scale(
    const float* __restrict__ X, const float* __restrict__ W,
    const float* __restrict__ dinv, unsigned short* __restrict__ Hs) {
  __shared__ float Xs[64][36];
  __shared__ float Ws[32][128];
  const int t = threadIdx.x;
  const int tx = t & 15;
  const int ty = t >> 4;
  const int row0 = blockIdx.x * 64;
  float acc[4][8];
#pragma unroll
  for (int i = 0; i < 4; ++i)
#pragma unroll
    for (int j = 0; j < 8; ++j) acc[i][j] = 0.f;

  const int lr = t >> 2;
  const int lk = (t & 3) * 8;
  const int wk = t >> 5;
  const int wc = (t & 31) * 4;

  for (int kc = 0; kc < 128; kc += 32) {
    if (row0 + lr < NN) {
      const float* xp = X + (size_t)(row0 + lr) * CH + kc + lk;
      *(float4*)&Xs[lr][lk] = *(const float4*)xp;
      *(float4*)&Xs[lr][lk + 4] = *(const float4*)(xp + 4);
    } else {
      float4 z = {0.f, 0.f, 0.f, 0.f};
      *(float4*)&Xs[lr][lk] = z;
      *(float4*)&Xs[lr][lk + 4] = z;
    }
#pragma unroll
    for (int i = 0; i < 4; ++i)
      *(float4*)&Ws[wk + 8 * i][wc] =
          *(const float4*)(W + (size_t)(kc + wk + 8 * i) * CH + wc);
    __syncthreads();
#pragma unroll
    for (int k = 0; k < 32; ++k) {
      float4 w0 = *(float4*)&Ws[k][tx * 8];
      float4 w1 = *(float4*)&Ws[k][tx * 8 + 4];
#pragma unroll
      for (int i = 0; i < 4; ++i) {
        float xv = Xs[ty * 4 + i][k];
        acc[i][0] += xv * w0.x; acc[i][1] += xv * w0.y;
        acc[i][2] += xv * w0.z; acc[i][3] += xv * w0.w;
        acc[i][4] += xv * w1.x; acc[i][5] += xv * w1.y;
        acc[i][6] += xv * w1.z; acc[i][7] += xv * w1.w;
      }
    }
    __syncthreads();
  }
#pragma unroll
  for (int i = 0; i < 4; ++i) {
    int r = row0 + ty * 4 + i;
    if (r < NN) {
      float d = dinv[r];
      uint4 u;
      u.x = pack2(d * acc[i][0], d * acc[i][1]);
      u.y = pack2(d * acc[i][2], d * acc[i][3]);
      u.z = pack2(d * acc[i][4], d * acc[i][5]);
      u.w = pack2(d * acc[i][6], d * acc[i][7]);
      *(uint4*)&Hs[(size_t)r * CH + tx * 8] = u;
    }
  }
}

// out[i] = relu(dinv[i]*(Hs[i] + sum_{e:dst=i} Hs[csr[e]]) + b). One wave per node.
// bf16x2 rows; fp32 accumulate; 8 gathers in flight per wave.
__global__ __launch_bounds__(256) void k_aggregate(
    const unsigned* __restrict__ H, const int* __restrict__ rows,
    const int* __restrict__ csr, const float* __restrict__ dinv,
    const float* __restrict__ bias, float* __restrict__ out) {
  int node = blockIdx.x * 4 + (threadIdx.x >> 6);
  int lane = threadIdx.x & 63;
  if (node >= NN) return;
  float bx = bias[2 * lane], by = bias[2 * lane + 1];  // hoisted, wave-invariant path
  unsigned sv = H[(size_t)node * 64 + lane];  // self-loop term
  float ax = bflo(sv), ay = bfhi(sv);
  int e = rows[node], e1 = rows[node + 1];
  for (; e + 8 <= e1; e += 8) {
    int j0 = csr[e],     j1 = csr[e + 1], j2 = csr[e + 2], j3 = csr[e + 3];
    int j4 = csr[e + 4], j5 = csr[e + 5], j6 = csr[e + 6], j7 = csr[e + 7];
    unsigned v0 = H[(size_t)j0 * 64 + lane];
    unsigned v1 = H[(size_t)j1 * 64 + lane];
    unsigned v2 = H[(size_t)j2 * 64 + lane];
    unsigned v3 = H[(size_t)j3 * 64 + lane];
    unsigned v4 = H[(size_t)j4 * 64 + lane];
    unsigned v5 = H[(size_t)j5 * 64 + lane];
    unsigned v6 = H[(size_t)j6 * 64 + lane];
    unsigned v7 = H[(size_t)j7 * 64 + lane];
    ax += ((bflo(v0) + bflo(v1)) + (bflo(v2) + bflo(v3))) +
          ((bflo(v4) + bflo(v5)) + (bflo(v6) + bflo(v7)));
    ay += ((bfhi(v0) + bfhi(v1)) + (bfhi(v2) + bfhi(v3))) +
          ((bfhi(v4) + bfhi(v5)) + (bfhi(v6) + bfhi(v7)));
  }
  if (e + 4 <= e1) {
    int j0 = csr[e], j1 = csr[e + 1], j2 = csr[e + 2], j3 = csr[e + 3];
    unsigned v0 = H[(size_t)j0 * 64 + lane];
    unsigned v1 = H[(size_t)j1 * 64 + lane];
    unsigned v2 = H[(size_t)j2 * 64 + lane];
    unsigned v3 = H[(size_t)j3 * 64 + lane];
    ax += (bflo(v0) + bflo(v1)) + (bflo(v2) + bflo(v3));
    ay += (bfhi(v0) + bfhi(v1)) + (bfhi(v2) + bfhi(v3));
    e += 4;
  }
  for (; e < e1; ++e) {
    unsigned v = H[(size_t)csr[e] * 64 + lane];
    ax += bflo(v);
    ay += bfhi(v);
  }
  float d = dinv[node];
  float2 o;
  o.x = fmaxf(fmaf(d, ax, bx), 0.f);
  o.y = fmaxf(fmaf(d, ay, by), 0.f);
  ((float2*)out)[(size_t)node * 64 + lane] = o;
}

// batch is sorted: graph g occupies nodes [start[g], start[g+1]).
__global__ void k_starts(const int* __restrict__ batch, int* __restrict__ start) {
  int i = blockIdx.x * 256 + threadIdx.x;
  if (i >= NN) return;
  int b = batch[i];
  int prev = (i == 0) ? -1 : batch[i - 1];
  for (int g = prev + 1; g <= b; ++g) start[g] = i;
  if (i == NN - 1)
    for (int g = b + 1; g <= NG; ++g) start[g] = NN;
}

// one block (2 waves) per graph: segmented mean, no atomics.
__global__ __launch_bounds__(256) void k_pool_mean(
    const float* __restrict__ A, const int* __restrict__ start,
    float* __restrict__ pooled) {
  __shared__ float part[128];
  int g = blockIdx.x;
  int c = threadIdx.x & 127;
  int half = threadIdx.x >> 7;
  int s0 = start[g], s1 = start[g + 1];
  float sum = 0.f;
  for (int i = s0 + half; i < s1; i += 2)
    sum += A[(size_t)i * CH + c];
  if (half) part[c] = sum;
  __syncthreads();
  if (!half) {
    sum += part[c];
    float n = fmaxf((float)(s1 - s0), 1.0f);
    pooled[(size_t)g * CH + c] = sum / n;
  }
}

__global__ void k_head1(const float* __restrict__ pooled,
                        const float* __restrict__ W3, const float* __restrict__ b3,
                        float* __restrict__ g1) {
  __shared__ float row[128];
  int g = blockIdx.x, c = threadIdx.x;
  row[c] = pooled[(size_t)g * CH + c];
  __syncthreads();
  float acc = b3[c];
  for (int k = 0; k < 128; ++k) acc += row[k] * W3[(size_t)k * CH + c];
  g1[(size_t)g * CH + c] = fmaxf(acc, 0.f);
}

__global__ void k_head2(const float* __restrict__ g1, const float* __restrict__ W4,
                        const float* __restrict__ b4, float* __restrict__ out) {
  __shared__ float row[128];
  int g = blockIdx.x, c = threadIdx.x;  // 64 threads
  row[c] = g1[(size_t)g * CH + c];
  row[c + 64] = g1[(size_t)g * CH + c + 64];
  __syncthreads();
  float acc = b4[c];
  for (int k = 0; k < 128; ++k) acc += row[k] * W4[(size_t)k * OC + c];
  out[(size_t)g * OC + c] = acc;
}

extern "C" void kernel_launch(void* const* d_in, const int* in_sizes, int n_in,
                              void* d_out, int out_size, void* d_ws, size_t ws_size,
                              hipStream_t stream) {
  const float* X   = (const float*)d_in[0];
  const int* ei    = (const int*)d_in[1];
  const int* batch = (const int*)d_in[2];
  const float* W1  = (const float*)d_in[3];
  const float* b1  = (const float*)d_in[4];
  const float* W2  = (const float*)d_in[5];
  const float* b2  = (const float*)d_in[6];
  const float* W3  = (const float*)d_in[7];
  const float* b3  = (const float*)d_in[8];
  const float* W4  = (const float*)d_in[9];
  const float* b4  = (const float*)d_in[10];
  float* out = (float*)d_out;
  float* ws = (float*)d_ws;

  const int* src = ei;        // edge_index[0]
  const int* dst = ei + EE;   // edge_index[1]

  float* dinv = ws + O_DINV;
  int* deg    = (int*)(ws + O_DEG);
  int* rows   = (int*)(ws + O_ROWS);
  int* curs   = (int*)(ws + O_CURS);
  int* part   = (int*)(ws + O_PART);
  int* offs   = (int*)(ws + O_OFFS);
  int* csr    = (int*)(ws + O_CSR);
  unsigned short* Hs = (unsigned short*)(ws + O_HS);
  float* A1   = ws + O_A1;
  int* start  = (int*)(ws + O_START);
  float* pool = ws + O_POOL;
  float* g1   = ws + O_G1;

  hipMemsetAsync(deg, 0, NN * sizeof(int), stream);
  hipMemsetAsync(curs, 0, NN * sizeof(int), stream);

  k_deg<<<(EE + 255) / 256, 256, 0, stream>>>(dst, deg);
  k_dinv<<<(NN + 255) / 256, 256, 0, stream>>>(deg, dinv);
  k_scan_block<<<98, 1024, 0, stream>>>(deg, rows, part);
  k_scan_part<<<1, 128, 0, stream>>>(part, offs);
  k_scan_add<<<(NN + 255) / 256, 256, 0, stream>>>(rows, offs);
  k_fill<<<(EE + 255) / 256, 256, 0, stream>>>(src, dst, rows, curs, csr);
  k_starts<<<(NN + 255) / 256, 256, 0, stream>>>(batch, start);

  // layer 1
  k_gemm_scale<<<(NN + 63) / 64, 256, 0, stream>>>(X, W1, dinv, Hs);
  k_aggregate<<<(NN + 3) / 4, 256, 0, stream>>>((const unsigned*)Hs, rows, csr, dinv, b1, A1);
  // layer 2
  k_gemm_scale<<<(NN + 63) / 64, 256, 0, stream>>>(A1, W2, dinv, Hs);
  k_aggregate<<<(NN + 3) / 4, 256, 0, stream>>>((const unsigned*)Hs, rows, csr, dinv, b2, A1);

  k_pool_mean<<<NG, 256, 0, stream>>>(A1, start, pool);
  k_head1<<<NG, 128, 0, stream>>>(pool, W3, b3, g1);
  k_head2<<<NG, 64, 0, stream>>>(g1, W4, b4, out);
}

// Round 6
// 515.401 us; speedup vs baseline: 1.6695x; 1.1078x over previous
//
#include <hip/hip_runtime.h>

#define NN 100000
#define EE 1600000
#define CH 128
#define NG 512
#define OC 64

// coarse radix partition: 98 buckets of 1024 nodes
#define CSH 10
#define NCB 98
#define CCAP 17408   // mean 16384 + 8 sigma
#define PBLK 160
#define PCHUNK 10000

// workspace element offsets (4-byte units)
#define O_DINV   0
#define O_DEG    100096
#define O_ROWS   200128
#define O_GCNT   300160
#define O_PART   400192
#define O_OFFS   400320
#define O_CSR    400448
#define O_HS     2000448   // bf16 Hs: NN*CH ushorts = 6.4M words
#define O_STG    5200448   // staging 1.71M words; inside Hs region, used only before Hs
#define O_A1     14800448
#define O_START  27600448
#define O_POOL   27601024
#define O_G1     27666560

static __device__ __forceinline__ unsigned short f2bf(float x) {
  unsigned u = __float_as_uint(x);
  return (unsigned short)((u + 0x7FFFu + ((u >> 16) & 1u)) >> 16);  // RNE
}
static __device__ __forceinline__ unsigned pack2(float a, float b) {
  return (unsigned)f2bf(a) | ((unsigned)f2bf(b) << 16);
}
static __device__ __forceinline__ float bflo(unsigned v) {
  return __uint_as_float(v << 16);
}
static __device__ __forceinline__ float bfhi(unsigned v) {
  return __uint_as_float(v & 0xFFFF0000u);
}

// Phase A: degree count + coarse partition. Per-block contiguous runs per bucket
// so stores merge in the local XCD L2. One reservation atomic per (block,bucket).
__global__ __launch_bounds__(256) void k_part(const int* __restrict__ src,
                                              const int* __restrict__ dst,
                                              int* __restrict__ deg,
                                              int* __restrict__ gcnt,
                                              unsigned* __restrict__ stg) {
  __shared__ int hist[NCB];
  __shared__ int base[NCB];
  __shared__ int cur[NCB];
  int t = threadIdx.x;
  int e0 = blockIdx.x * PCHUNK;
  int e1 = min(e0 + PCHUNK, EE);
  for (int i = t; i < NCB; i += 256) { hist[i] = 0; cur[i] = 0; }
  __syncthreads();
  for (int e = e0 + t; e < e1; e += 256) {
    int d = dst[e];
    atomicAdd(&deg[d], 1);
    atomicAdd(&hist[d >> CSH], 1);
  }
  __syncthreads();
  for (int i = t; i < NCB; i += 256) base[i] = atomicAdd(&gcnt[i], hist[i]);
  __syncthreads();
  for (int e = e0 + t; e < e1; e += 256) {
    int d = dst[e];
    int b = d >> CSH;
    int pos = atomicAdd(&cur[b], 1);
    stg[(size_t)b * CCAP + base[b] + pos] =
        (unsigned)src[e] | ((unsigned)(d & 1023) << 17);
  }
}

// Phase B: one block per bucket; LDS cursors; stores confined to the block's
// exclusive CSR segment (~65 KB) -> full L2 write-merging.
__global__ __launch_bounds__(256) void k_csr(const unsigned* __restrict__ stg,
                                             const int* __restrict__ gcnt,
                                             const int* __restrict__ rows,
                                             int* __restrict__ csr) {
  __shared__ int lrow[1025];
  __shared__ int lcur[1024];
  int b = blockIdx.x;
  int t = threadIdx.x;
  int nbase = b << CSH;
  int ncnt = min(1024, NN - nbase);
  for (int i = t; i <= ncnt; i += 256) lrow[i] = rows[nbase + i];
  for (int i = t; i < 1024; i += 256) lcur[i] = 0;
  __syncthreads();
  int cnt = gcnt[b];
  for (int e = t; e < cnt; e += 256) {
    unsigned w = stg[(size_t)b * CCAP + e];
    int ld = w >> 17;
    int s = (int)(w & 0x1FFFFu);
    int p = atomicAdd(&lcur[ld], 1);
    csr[lrow[ld] + p] = s;
  }
}

__global__ void k_dinv(const int* __restrict__ deg, float* __restrict__ dinv) {
  int i = blockIdx.x * 256 + threadIdx.x;
  if (i < NN) dinv[i] = rsqrtf((float)(deg[i] + 1));  // +1 self-loop
}

__global__ __launch_bounds__(1024) void k_scan_block(const int* __restrict__ deg,
                                                     int* __restrict__ rows,
                                                     int* __restrict__ part) {
  __shared__ int s[1024];
  int t = threadIdx.x;
  int gid = blockIdx.x * 1024 + t;
  int v = (gid < NN) ? deg[gid] : 0;
  s[t] = v;
  __syncthreads();
  for (int off = 1; off < 1024; off <<= 1) {
    int u = (t >= off) ? s[t - off] : 0;
    __syncthreads();
    if (t >= off) s[t] += u;
    __syncthreads();
  }
  if (gid < NN) rows[gid] = s[t] - v;       // exclusive
  if (t == 1023) part[blockIdx.x] = s[t];   // block total
}

__global__ void k_scan_part(const int* __restrict__ part, int* __restrict__ offs) {
  __shared__ int s[128];
  int t = threadIdx.x;
  int v = (t < 98) ? part[t] : 0;
  s[t] = v;
  __syncthreads();
  for (int off = 1; off < 128; off <<= 1) {
    int u = (t >= off) ? s[t - off] : 0;
    __syncthreads();
    if (t >= off) s[t] += u;
    __syncthreads();
  }
  if (t < 98) offs[t] = s[t] - v;
}

__global__ void k_scan_add(int* __restrict__ rows, const int* __restrict__ offs) {
  int i = blockIdx.x * 256 + threadIdx.x;
  if (i < NN) rows[i] += offs[i >> 10];
  if (i == 0) rows[NN] = EE;
}

// Hs(bf16) = diag(dinv) * (X @ W).  64-row tile, 256 threads, 4x8 register tile.
__global__ __launch_bounds__(256) void k_gemm_scale(
    const float* __restrict__ X, const float* __restrict__ W,
    const float* __restrict__ dinv, unsigned short* __restrict__ Hs) {
  __shared__ float Xs[64][36];
  __shared__ float Ws[32][128];
  const int t = threadIdx.x;
  const int tx = t & 15;
  const int ty = t >> 4;
  const int row0 = blockIdx.x * 64;
  float acc[4][8];
#pragma unroll
  for (int i = 0; i < 4; ++i)
#pragma unroll
    for (int j = 0; j < 8; ++j) acc[i][j] = 0.f;

  const int lr = t >> 2;
  const int lk = (t & 3) * 8;
  const int wk = t >> 5;
  const int wc = (t & 31) * 4;

  for (int kc = 0; kc < 128; kc += 32) {
    if (row0 + lr < NN) {
      const float* xp = X + (size_t)(row0 + lr) * CH + kc + lk;
      *(float4*)&Xs[lr][lk] = *(const float4*)xp;
      *(float4*)&Xs[lr][lk + 4] = *(const float4*)(xp + 4);
    } else {
      float4 z = {0.f, 0.f, 0.f, 0.f};
      *(float4*)&Xs[lr][lk] = z;
      *(float4*)&Xs[lr][lk + 4] = z;
    }
#pragma unroll
    for (int i = 0; i < 4; ++i)
      *(float4*)&Ws[wk + 8 * i][wc] =
          *(const float4*)(W + (size_t)(kc + wk + 8 * i) * CH + wc);
    __syncthreads();
#pragma unroll
    for (int k = 0; k < 32; ++k) {
      float4 w0 = *(float4*)&Ws[k][tx * 8];
      float4 w1 = *(float4*)&Ws[k][tx * 8 + 4];
#pragma unroll
      for (int i = 0; i < 4; ++i) {
        float xv = Xs[ty * 4 + i][k];
        acc[i][0] += xv * w0.x; acc[i][1] += xv * w0.y;
        acc[i][2] += xv * w0.z; acc[i][3] += xv * w0.w;
        acc[i][4] += xv * w1.x; acc[i][5] += xv * w1.y;
        acc[i][6] += xv * w1.z; acc[i][7] += xv * w1.w;
      }
    }
    __syncthreads();
  }
#pragma unroll
  for (int i = 0; i < 4; ++i) {
    int r = row0 + ty * 4 + i;
    if (r < NN) {
      float d = dinv[r];
      uint4 u;
      u.x = pack2(d * acc[i][0], d * acc[i][1]);
      u.y = pack2(d * acc[i][2], d * acc[i][3]);
      u.z = pack2(d * acc[i][4], d * acc[i][5]);
      u.w = pack2(d * acc[i][6], d * acc[i][7]);
      *(uint4*)&Hs[(size_t)r * CH + tx * 8] = u;
    }
  }
}

// out[i] = relu(dinv[i]*(Hs[i] + sum_{e:dst=i} Hs[csr[e]]) + b). One wave per node.
__global__ __launch_bounds__(256) void k_aggregate(
    const unsigned* __restrict__ H, const int* __restrict__ rows,
    const int* __restrict__ csr, const float* __restrict__ dinv,
    const float* __restrict__ bias, float* __restrict__ out) {
  int node = blockIdx.x * 4 + (threadIdx.x >> 6);
  int lane = threadIdx.x & 63;
  if (node >= NN) return;
  float bx = bias[2 * lane], by = bias[2 * lane + 1];
  unsigned sv = H[(size_t)node * 64 + lane];  // self-loop term
  float ax = bflo(sv), ay = bfhi(sv);
  int e = rows[node], e1 = rows[node + 1];
  for (; e + 8 <= e1; e += 8) {
    int j0 = csr[e],     j1 = csr[e + 1], j2 = csr[e + 2], j3 = csr[e + 3];
    int j4 = csr[e + 4], j5 = csr[e + 5], j6 = csr[e + 6], j7 = csr[e + 7];
    unsigned v0 = H[(size_t)j0 * 64 + lane];
    unsigned v1 = H[(size_t)j1 * 64 + lane];
    unsigned v2 = H[(size_t)j2 * 64 + lane];
    unsigned v3 = H[(size_t)j3 * 64 + lane];
    unsigned v4 = H[(size_t)j4 * 64 + lane];
    unsigned v5 = H[(size_t)j5 * 64 + lane];
    unsigned v6 = H[(size_t)j6 * 64 + lane];
    unsigned v7 = H[(size_t)j7 * 64 + lane];
    ax += ((bflo(v0) + bflo(v1)) + (bflo(v2) + bflo(v3))) +
          ((bflo(v4) + bflo(v5)) + (bflo(v6) + bflo(v7)));
    ay += ((bfhi(v0) + bfhi(v1)) + (bfhi(v2) + bfhi(v3))) +
          ((bfhi(v4) + bfhi(v5)) + (bfhi(v6) + bfhi(v7)));
  }
  if (e + 4 <= e1) {
    int j0 = csr[e], j1 = csr[e + 1], j2 = csr[e + 2], j3 = csr[e + 3];
    unsigned v0 = H[(size_t)j0 * 64 + lane];
    unsigned v1 = H[(size_t)j1 * 64 + lane];
    unsigned v2 = H[(size_t)j2 * 64 + lane];
    unsigned v3 = H[(size_t)j3 * 64 + lane];
    ax += (bflo(v0) + bflo(v1)) + (bflo(v2) + bflo(v3));
    ay += (bfhi(v0) + bfhi(v1)) + (bfhi(v2) + bfhi(v3));
    e += 4;
  }
  for (; e < e1; ++e) {
    unsigned v = H[(size_t)csr[e] * 64 + lane];
    ax += bflo(v);
    ay += bfhi(v);
  }
  float d = dinv[node];
  float2 o;
  o.x = fmaxf(fmaf(d, ax, bx), 0.f);
  o.y = fmaxf(fmaf(d, ay, by), 0.f);
  ((float2*)out)[(size_t)node * 64 + lane] = o;
}

// batch is sorted: graph g occupies nodes [start[g], start[g+1]).
__global__ void k_starts(const int* __restrict__ batch, int* __restrict__ start) {
  int i = blockIdx.x * 256 + threadIdx.x;
  if (i >= NN) return;
  int b = batch[i];
  int prev = (i == 0) ? -1 : batch[i - 1];
  for (int g = prev + 1; g <= b; ++g) start[g] = i;
  if (i == NN - 1)
    for (int g = b + 1; g <= NG; ++g) start[g] = NN;
}

// one block (2 waves) per graph: segmented mean, no atomics.
__global__ __launch_bounds__(256) void k_pool_mean(
    const float* __restrict__ A, const int* __restrict__ start,
    float* __restrict__ pooled) {
  __shared__ float part[128];
  int g = blockIdx.x;
  int c = threadIdx.x & 127;
  int half = threadIdx.x >> 7;
  int s0 = start[g], s1 = start[g + 1];
  float sum = 0.f;
  for (int i = s0 + half; i < s1; i += 2)
    sum += A[(size_t)i * CH + c];
  if (half) part[c] = sum;
  __syncthreads();
  if (!half) {
    sum += part[c];
    float n = fmaxf((float)(s1 - s0), 1.0f);
    pooled[(size_t)g * CH + c] = sum / n;
  }
}

__global__ void k_head1(const float* __restrict__ pooled,
                        const float* __restrict__ W3, const float* __restrict__ b3,
                        float* __restrict__ g1) {
  __shared__ float row[128];
  int g = blockIdx.x, c = threadIdx.x;
  row[c] = pooled[(size_t)g * CH + c];
  __syncthreads();
  float acc = b3[c];
  for (int k = 0; k < 128; ++k) acc += row[k] * W3[(size_t)k * CH + c];
  g1[(size_t)g * CH + c] = fmaxf(acc, 0.f);
}

__global__ void k_head2(const float* __restrict__ g1, const float* __restrict__ W4,
                        const float* __restrict__ b4, float* __restrict__ out) {
  __shared__ float row[128];
  int g = blockIdx.x, c = threadIdx.x;  // 64 threads
  row[c] = g1[(size_t)g * CH + c];
  row[c + 64] = g1[(size_t)g * CH + c + 64];
  __syncthreads();
  float acc = b4[c];
  for (int k = 0; k < 128; ++k) acc += row[k] * W4[(size_t)k * OC + c];
  out[(size_t)g * OC + c] = acc;
}

extern "C" void kernel_launch(void* const* d_in, const int* in_sizes, int n_in,
                              void* d_out, int out_size, void* d_ws, size_t ws_size,
                              hipStream_t stream) {
  const float* X   = (const float*)d_in[0];
  const int* ei    = (const int*)d_in[1];
  const int* batch = (const int*)d_in[2];
  const float* W1  = (const float*)d_in[3];
  const float* b1  = (const float*)d_in[4];
  const float* W2  = (const float*)d_in[5];
  const float* b2  = (const float*)d_in[6];
  const float* W3  = (const float*)d_in[7];
  const float* b3  = (const float*)d_in[8];
  const float* W4  = (const float*)d_in[9];
  const float* b4  = (const float*)d_in[10];
  float* out = (float*)d_out;
  float* ws = (float*)d_ws;

  const int* src = ei;        // edge_index[0]
  const int* dst = ei + EE;   // edge_index[1]

  float* dinv = ws + O_DINV;
  int* deg    = (int*)(ws + O_DEG);
  int* rows   = (int*)(ws + O_ROWS);
  int* gcnt   = (int*)(ws + O_GCNT);
  int* part   = (int*)(ws + O_PART);
  int* offs   = (int*)(ws + O_OFFS);
  int* csr    = (int*)(ws + O_CSR);
  unsigned short* Hs = (unsigned short*)(ws + O_HS);
  unsigned* stg = (unsigned*)(ws + O_STG);
  float* A1   = ws + O_A1;
  int* start  = (int*)(ws + O_START);
  float* pool = ws + O_POOL;
  float* g1   = ws + O_G1;

  hipMemsetAsync(deg, 0, NN * sizeof(int), stream);
  hipMemsetAsync(gcnt, 0, NCB * sizeof(int), stream);

  k_part<<<PBLK, 256, 0, stream>>>(src, dst, deg, gcnt, stg);
  k_dinv<<<(NN + 255) / 256, 256, 0, stream>>>(deg, dinv);
  k_scan_block<<<98, 1024, 0, stream>>>(deg, rows, part);
  k_scan_part<<<1, 128, 0, stream>>>(part, offs);
  k_scan_add<<<(NN + 255) / 256, 256, 0, stream>>>(rows, offs);
  k_csr<<<NCB, 256, 0, stream>>>(stg, gcnt, rows, csr);
  k_starts<<<(NN + 255) / 256, 256, 0, stream>>>(batch, start);

  // layer 1
  k_gemm_scale<<<(NN + 63) / 64, 256, 0, stream>>>(X, W1, dinv, Hs);
  k_aggregate<<<(NN + 3) / 4, 256, 0, stream>>>((const unsigned*)Hs, rows, csr, dinv, b1, A1);
  // layer 2
  k_gemm_scale<<<(NN + 63) / 64, 256, 0, stream>>>(A1, W2, dinv, Hs);
  k_aggregate<<<(NN + 3) / 4, 256, 0, stream>>>((const unsigned*)Hs, rows, csr, dinv, b2, A1);

  k_pool_mean<<<NG, 256, 0, stream>>>(A1, start, pool);
  k_head1<<<NG, 128, 0, stream>>>(pool, W3, b3, g1);
  k_head2<<<NG, 64, 0, stream>>>(g1, W4, b4, out);
}

// Round 7
// 482.282 us; speedup vs baseline: 1.7842x; 1.0687x over previous
//
#include <hip/hip_runtime.h>

#define NN 100000
#define EE 1600000
#define CH 128
#define NG 512
#define OC 64

// coarse radix partition: 98 buckets of 1024 nodes; fixed-capacity staging cells
#define CSH 10
#define NCB 98
#define PBLK 256
#define PCHUNK 6250     // 256*6250 = 1.6M exactly
#define SCAP 128        // per (block,bucket) cell: mean 63.8 + 8 sigma

// workspace element offsets (4-byte units)
#define O_DINV   0
#define O_DEG    100096
#define O_ROWS   200128
#define O_CNT    300160   // 256*98 = 25088 per-cell counts
#define O_PART   400192
#define O_OFFS   400320
#define O_CSR    400448
#define O_HS     2000448  // bf16 Hs: NN*CH ushorts = 6.4M words (ends 8400448)
#define O_STG    5200448  // staging 256*98*128 = 3.21M words (ends 8411712); dead before Hs written
#define O_A1     14800448
#define O_START  27600448
#define O_POOL   27601024
#define O_G1     27666560

static __device__ __forceinline__ unsigned short f2bf(float x) {
  unsigned u = __float_as_uint(x);
  return (unsigned short)((u + 0x7FFFu + ((u >> 16) & 1u)) >> 16);  // RNE
}
static __device__ __forceinline__ unsigned pack2(float a, float b) {
  return (unsigned)f2bf(a) | ((unsigned)f2bf(b) << 16);
}
static __device__ __forceinline__ float bflo(unsigned v) {
  return __uint_as_float(v << 16);
}
static __device__ __forceinline__ float bfhi(unsigned v) {
  return __uint_as_float(v & 0xFFFF0000u);
}

// Single-pass: degree count + partition into private per-(block,bucket) cells.
// No global reservations; LDS cursors only. 1024 threads for occupancy.
__global__ __launch_bounds__(1024) void k_part(const int* __restrict__ src,
                                               const int* __restrict__ dst,
                                               int* __restrict__ deg,
                                               int* __restrict__ cnt,
                                               unsigned* __restrict__ stg) {
  __shared__ int cur[NCB];
  int t = threadIdx.x;
  int e0 = blockIdx.x * PCHUNK;
  int e1 = min(e0 + PCHUNK, EE);
  if (t < NCB) cur[t] = 0;
  __syncthreads();
  unsigned* mystg = stg + (size_t)blockIdx.x * NCB * SCAP;
  for (int e = e0 + t; e < e1; e += 1024) {
    int d = dst[e];
    atomicAdd(&deg[d], 1);           // fire-and-forget, 16/address avg
    int b = d >> CSH;
    int p = atomicAdd(&cur[b], 1);   // LDS
    if (p < SCAP)
      mystg[b * SCAP + p] = (unsigned)src[e] | ((unsigned)(d & 1023) << 17);
  }
  __syncthreads();
  if (t < NCB) cnt[blockIdx.x * NCB + t] = min(cur[t], SCAP);
}

// One block per bucket; 16 waves each walk their own sub-run chain (latency overlap).
// Stores confined to the bucket's exclusive ~65 KB CSR segment -> L2 write-merging.
__global__ __launch_bounds__(1024) void k_csr(const unsigned* __restrict__ stg,
                                              const int* __restrict__ cnt,
                                              const int* __restrict__ rows,
                                              int* __restrict__ csr) {
  __shared__ int lrow[1025];
  __shared__ int lcur[1024];
  int b = blockIdx.x;
  int t = threadIdx.x;
  int w = t >> 6, lane = t & 63;
  int nbase = b << CSH;
  int ncnt = min(1024, NN - nbase);
  if (t <= ncnt) lrow[t] = rows[nbase + t];
  lcur[t] = 0;
  __syncthreads();
  for (int blk = w; blk < PBLK; blk += 16) {
    int c = cnt[blk * NCB + b];
    const unsigned* p = stg + ((size_t)blk * NCB + b) * SCAP;
    for (int e = lane; e < c; e += 64) {
      unsigned x = p[e];
      int ld = x >> 17;
      int q = atomicAdd(&lcur[ld], 1);
      csr[lrow[ld] + q] = (int)(x & 0x1FFFFu);
    }
  }
}

// scan over degrees (1024 nodes/block) + fused dinv computation.
__global__ __launch_bounds__(1024) void k_scan_block(const int* __restrict__ deg,
                                                     int* __restrict__ rows,
                                                     int* __restrict__ part,
                                                     float* __restrict__ dinv) {
  __shared__ int s[1024];
  int t = threadIdx.x;
  int gid = blockIdx.x * 1024 + t;
  int v = (gid < NN) ? deg[gid] : 0;
  if (gid < NN) dinv[gid] = rsqrtf((float)(v + 1));  // +1 self-loop
  s[t] = v;
  __syncthreads();
  for (int off = 1; off < 1024; off <<= 1) {
    int u = (t >= off) ? s[t - off] : 0;
    __syncthreads();
    if (t >= off) s[t] += u;
    __syncthreads();
  }
  if (gid < NN) rows[gid] = s[t] - v;       // exclusive
  if (t == 1023) part[blockIdx.x] = s[t];   // block total
}

__global__ void k_scan_part(const int* __restrict__ part, int* __restrict__ offs) {
  __shared__ int s[128];
  int t = threadIdx.x;
  int v = (t < 98) ? part[t] : 0;
  s[t] = v;
  __syncthreads();
  for (int off = 1; off < 128; off <<= 1) {
    int u = (t >= off) ? s[t - off] : 0;
    __syncthreads();
    if (t >= off) s[t] += u;
    __syncthreads();
  }
  if (t < 98) offs[t] = s[t] - v;
}

// scan finalize + fused batch-starts (both 100k-range, independent).
__global__ void k_scan_add(int* __restrict__ rows, const int* __restrict__ offs,
                           const int* __restrict__ batch, int* __restrict__ start) {
  int i = blockIdx.x * 256 + threadIdx.x;
  if (i >= NN) return;
  rows[i] += offs[i >> 10];
  if (i == 0) rows[NN] = EE;
  int b = batch[i];
  int prev = (i == 0) ? -1 : batch[i - 1];
  for (int g = prev + 1; g <= b; ++g) start[g] = i;
  if (i == NN - 1)
    for (int g = b + 1; g <= NG; ++g) start[g] = NN;
}

// Hs(bf16) = diag(dinv) * (X @ W).  64-row tile, 256 threads, 4x8 register tile.
__global__ __launch_bounds__(256) void k_gemm_scale(
    const float* __restrict__ X, const float* __restrict__ W,
    const float* __restrict__ dinv, unsigned short* __restrict__ Hs) {
  __shared__ float Xs[64][36];
  __shared__ float Ws[32][128];
  const int t = threadIdx.x;
  const int tx = t & 15;
  const int ty = t >> 4;
  const int row0 = blockIdx.x * 64;
  float acc[4][8];
#pragma unroll
  for (int i = 0; i < 4; ++i)
#pragma unroll
    for (int j = 0; j < 8; ++j) acc[i][j] = 0.f;

  const int lr = t >> 2;
  const int lk = (t & 3) * 8;
  const int wk = t >> 5;
  const int wc = (t & 31) * 4;

  for (int kc = 0; kc < 128; kc += 32) {
    if (row0 + lr < NN) {
      const float* xp = X + (size_t)(row0 + lr) * CH + kc + lk;
      *(float4*)&Xs[lr][lk] = *(const float4*)xp;
      *(float4*)&Xs[lr][lk + 4] = *(const float4*)(xp + 4);
    } else {
      float4 z = {0.f, 0.f, 0.f, 0.f};
      *(float4*)&Xs[lr][lk] = z;
      *(float4*)&Xs[lr][lk + 4] = z;
    }
#pragma unroll
    for (int i = 0; i < 4; ++i)
      *(float4*)&Ws[wk + 8 * i][wc] =
          *(const float4*)(W + (size_t)(kc + wk + 8 * i) * CH + wc);
    __syncthreads();
#pragma unroll
    for (int k = 0; k < 32; ++k) {
      float4 w0 = *(float4*)&Ws[k][tx * 8];
      float4 w1 = *(float4*)&Ws[k][tx * 8 + 4];
#pragma unroll
      for (int i = 0; i < 4; ++i) {
        float xv = Xs[ty * 4 + i][k];
        acc[i][0] += xv * w0.x; acc[i][1] += xv * w0.y;
        acc[i][2] += xv * w0.z; acc[i][3] += xv * w0.w;
        acc[i][4] += xv * w1.x; acc[i][5] += xv * w1.y;
        acc[i][6] += xv * w1.z; acc[i][7] += xv * w1.w;
      }
    }
    __syncthreads();
  }
#pragma unroll
  for (int i = 0; i < 4; ++i) {
    int r = row0 + ty * 4 + i;
    if (r < NN) {
      float d = dinv[r];
      uint4 u;
      u.x = pack2(d * acc[i][0], d * acc[i][1]);
      u.y = pack2(d * acc[i][2], d * acc[i][3]);
      u.z = pack2(d * acc[i][4], d * acc[i][5]);
      u.w = pack2(d * acc[i][6], d * acc[i][7]);
      *(uint4*)&Hs[(size_t)r * CH + tx * 8] = u;
    }
  }
}

// out[i] = relu(dinv[i]*(Hs[i] + sum_{e:dst=i} Hs[csr[e]]) + b). One wave per node.
__global__ __launch_bounds__(256) void k_aggregate(
    const unsigned* __restrict__ H, const int* __restrict__ rows,
    const int* __restrict__ csr, const float* __restrict__ dinv,
    const float* __restrict__ bias, float* __restrict__ out) {
  int node = blockIdx.x * 4 + (threadIdx.x >> 6);
  int lane = threadIdx.x & 63;
  if (node >= NN) return;
  float bx = bias[2 * lane], by = bias[2 * lane + 1];
  unsigned sv = H[(size_t)node * 64 + lane];  // self-loop term
  float ax = bflo(sv), ay = bfhi(sv);
  int e = rows[node], e1 = rows[node + 1];
  for (; e + 8 <= e1; e += 8) {
    int j0 = csr[e],     j1 = csr[e + 1], j2 = csr[e + 2], j3 = csr[e + 3];
    int j4 = csr[e + 4], j5 = csr[e + 5], j6 = csr[e + 6], j7 = csr[e + 7];
    unsigned v0 = H[(size_t)j0 * 64 + lane];
    unsigned v1 = H[(size_t)j1 * 64 + lane];
    unsigned v2 = H[(size_t)j2 * 64 + lane];
    unsigned v3 = H[(size_t)j3 * 64 + lane];
    unsigned v4 = H[(size_t)j4 * 64 + lane];
    unsigned v5 = H[(size_t)j5 * 64 + lane];
    unsigned v6 = H[(size_t)j6 * 64 + lane];
    unsigned v7 = H[(size_t)j7 * 64 + lane];
    ax += ((bflo(v0) + bflo(v1)) + (bflo(v2) + bflo(v3))) +
          ((bflo(v4) + bflo(v5)) + (bflo(v6) + bflo(v7)));
    ay += ((bfhi(v0) + bfhi(v1)) + (bfhi(v2) + bfhi(v3))) +
          ((bfhi(v4) + bfhi(v5)) + (bfhi(v6) + bfhi(v7)));
  }
  if (e + 4 <= e1) {
    int j0 = csr[e], j1 = csr[e + 1], j2 = csr[e + 2], j3 = csr[e + 3];
    unsigned v0 = H[(size_t)j0 * 64 + lane];
    unsigned v1 = H[(size_t)j1 * 64 + lane];
    unsigned v2 = H[(size_t)j2 * 64 + lane];
    unsigned v3 = H[(size_t)j3 * 64 + lane];
    ax += (bflo(v0) + bflo(v1)) + (bflo(v2) + bflo(v3));
    ay += (bfhi(v0) + bfhi(v1)) + (bfhi(v2) + bfhi(v3));
    e += 4;
  }
  for (; e < e1; ++e) {
    unsigned v = H[(size_t)csr[e] * 64 + lane];
    ax += bflo(v);
    ay += bfhi(v);
  }
  float d = dinv[node];
  float2 o;
  o.x = fmaxf(fmaf(d, ax, bx), 0.f);
  o.y = fmaxf(fmaf(d, ay, by), 0.f);
  ((float2*)out)[(size_t)node * 64 + lane] = o;
}

// one block (2 waves) per graph: segmented mean, no atomics.
__global__ __launch_bounds__(256) void k_pool_mean(
    const float* __restrict__ A, const int* __restrict__ start,
    float* __restrict__ pooled) {
  __shared__ float part[128];
  int g = blockIdx.x;
  int c = threadIdx.x & 127;
  int half = threadIdx.x >> 7;
  int s0 = start[g], s1 = start[g + 1];
  float sum = 0.f;
  for (int i = s0 + half; i < s1; i += 2)
    sum += A[(size_t)i * CH + c];
  if (half) part[c] = sum;
  __syncthreads();
  if (!half) {
    sum += part[c];
    float n = fmaxf((float)(s1 - s0), 1.0f);
    pooled[(size_t)g * CH + c] = sum / n;
  }
}

__global__ void k_head1(const float* __restrict__ pooled,
                        const float* __restrict__ W3, const float* __restrict__ b3,
                        float* __restrict__ g1) {
  __shared__ float row[128];
  int g = blockIdx.x, c = threadIdx.x;
  row[c] = pooled[(size_t)g * CH + c];
  __syncthreads();
  float acc = b3[c];
  for (int k = 0; k < 128; ++k) acc += row[k] * W3[(size_t)k * CH + c];
  g1[(size_t)g * CH + c] = fmaxf(acc, 0.f);
}

__global__ void k_head2(const float* __restrict__ g1, const float* __restrict__ W4,
                        const float* __restrict__ b4, float* __restrict__ out) {
  __shared__ float row[128];
  int g = blockIdx.x, c = threadIdx.x;  // 64 threads
  row[c] = g1[(size_t)g * CH + c];
  row[c + 64] = g1[(size_t)g * CH + c + 64];
  __syncthreads();
  float acc = b4[c];
  for (int k = 0; k < 128; ++k) acc += row[k] * W4[(size_t)k * OC + c];
  out[(size_t)g * OC + c] = acc;
}

extern "C" void kernel_launch(void* const* d_in, const int* in_sizes, int n_in,
                              void* d_out, int out_size, void* d_ws, size_t ws_size,
                              hipStream_t stream) {
  const float* X   = (const float*)d_in[0];
  const int* ei    = (const int*)d_in[1];
  const int* batch = (const int*)d_in[2];
  const float* W1  = (const float*)d_in[3];
  const float* b1  = (const float*)d_in[4];
  const float* W2  = (const float*)d_in[5];
  const float* b2  = (const float*)d_in[6];
  const float* W3  = (const float*)d_in[7];
  const float* b3  = (const float*)d_in[8];
  const float* W4  = (const float*)d_in[9];
  const float* b4  = (const float*)d_in[10];
  float* out = (float*)d_out;
  float* ws = (float*)d_ws;

  const int* src = ei;        // edge_index[0]
  const int* dst = ei + EE;   // edge_index[1]

  float* dinv = ws + O_DINV;
  int* deg    = (int*)(ws + O_DEG);
  int* rows   = (int*)(ws + O_ROWS);
  int* cnt    = (int*)(ws + O_CNT);
  int* part   = (int*)(ws + O_PART);
  int* offs   = (int*)(ws + O_OFFS);
  int* csr    = (int*)(ws + O_CSR);
  unsigned short* Hs = (unsigned short*)(ws + O_HS);
  unsigned* stg = (unsigned*)(ws + O_STG);
  float* A1   = ws + O_A1;
  int* start  = (int*)(ws + O_START);
  float* pool = ws + O_POOL;
  float* g1   = ws + O_G1;

  hipMemsetAsync(deg, 0, NN * sizeof(int), stream);

  k_part<<<PBLK, 1024, 0, stream>>>(src, dst, deg, cnt, stg);
  k_scan_block<<<98, 1024, 0, stream>>>(deg, rows, part, dinv);
  k_scan_part<<<1, 128, 0, stream>>>(part, offs);
  k_scan_add<<<(NN + 255) / 256, 256, 0, stream>>>(rows, offs, batch, start);
  k_csr<<<NCB, 1024, 0, stream>>>(stg, cnt, rows, csr);

  // layer 1
  k_gemm_scale<<<(NN + 63) / 64, 256, 0, stream>>>(X, W1, dinv, Hs);
  k_aggregate<<<(NN + 3) / 4, 256, 0, stream>>>((const unsigned*)Hs, rows, csr, dinv, b1, A1);
  // layer 2
  k_gemm_scale<<<(NN + 63) / 64, 256, 0, stream>>>(A1, W2, dinv, Hs);
  k_aggregate<<<(NN + 3) / 4, 256, 0, stream>>>((const unsigned*)Hs, rows, csr, dinv, b2, A1);

  k_pool_mean<<<NG, 256, 0, stream>>>(A1, start, pool);
  k_head1<<<NG, 128, 0, stream>>>(pool, W3, b3, g1);
  k_head2<<<NG, 64, 0, stream>>>(g1, W4, b4, out);
}

// Round 8
// 437.053 us; speedup vs baseline: 1.9688x; 1.1035x over previous
//
#include <hip/hip_runtime.h>

#define NN 100000
#define EE 1600000
#define CH 128
#define NG 512
#define OC 64

// coarse radix partition: 98 buckets of 1024 nodes; fixed-capacity staging cells
#define CSH 10
#define NCB 98
#define PBLK 256
#define PCHUNK 6250     // 256*6250 = 1.6M exactly
#define SCAP 128        // per (block,bucket) cell: mean 63.8 + 8 sigma

// workspace element offsets (4-byte units)
#define O_DINV   0
#define O_ROWS   200128
#define O_CNT    300160   // 256*98 = 25088 per-cell counts
#define O_PART   400192
#define O_OFFS   400320
#define O_CSR    400448
#define O_HS     2000448  // bf16 Hs: NN*CH ushorts = 6.4M words (ends 8400448)
#define O_STG    8400448  // staging 256*98*128 = 3.21M words
#define O_A1     14800448
#define O_START  27600448
#define O_POOL   27601024
#define O_G1     27666560

static __device__ __forceinline__ unsigned short f2bf(float x) {
  unsigned u = __float_as_uint(x);
  return (unsigned short)((u + 0x7FFFu + ((u >> 16) & 1u)) >> 16);  // RNE
}
static __device__ __forceinline__ unsigned pack2(float a, float b) {
  return (unsigned)f2bf(a) | ((unsigned)f2bf(b) << 16);
}
static __device__ __forceinline__ float bflo(unsigned v) {
  return __uint_as_float(v << 16);
}
static __device__ __forceinline__ float bfhi(unsigned v) {
  return __uint_as_float(v & 0xFFFF0000u);
}

// LDS radix scatter: hist -> scan -> ordered LDS buffer -> contiguous run copies.
// All global stores are line-dense; no global atomics at all.
__global__ __launch_bounds__(1024) void k_part(const int* __restrict__ src,
                                               const int* __restrict__ dst,
                                               int* __restrict__ cnt,
                                               unsigned* __restrict__ stg) {
  __shared__ int hist[NCB];   // counts, then exclusive bases
  __shared__ int lcur[NCB];
  __shared__ unsigned lout[PCHUNK];
  int t = threadIdx.x;
  int e0 = blockIdx.x * PCHUNK;
  if (t < NCB) { hist[t] = 0; lcur[t] = 0; }
  __syncthreads();
  for (int e = e0 + t; e < e0 + PCHUNK; e += 1024)
    atomicAdd(&hist[dst[e] >> CSH], 1);
  __syncthreads();
  if (t == 0) {  // serial exclusive scan over 98 — negligible
    int s = 0;
    for (int i = 0; i < NCB; ++i) { int v = hist[i]; hist[i] = s; s += v; }
  }
  __syncthreads();
  for (int e = e0 + t; e < e0 + PCHUNK; e += 1024) {
    int d = dst[e];
    int b = d >> CSH;
    int p = hist[b] + atomicAdd(&lcur[b], 1);
    lout[p] = (unsigned)src[e] | ((unsigned)(d & 1023) << 17);
  }
  __syncthreads();
  int w = t >> 6, lane = t & 63;
  unsigned* mystg = stg + (size_t)blockIdx.x * NCB * SCAP;
  for (int b = w; b < NCB; b += 16) {
    int beg = hist[b];
    int end = (b == NCB - 1) ? PCHUNK : hist[b + 1];
    int n = min(end - beg, SCAP);
    for (int i = lane; i < n; i += 64) mystg[b * SCAP + i] = lout[beg + i];
    if (lane == 0) cnt[blockIdx.x * NCB + b] = n;
  }
}

// Per bucket: local degree histogram from staging, fused dinv + local exclusive
// scan into rows + bucket total. Replaces global deg atomics entirely.
__global__ __launch_bounds__(1024) void k_count(const unsigned* __restrict__ stg,
                                                const int* __restrict__ cnt,
                                                int* __restrict__ rows,
                                                int* __restrict__ part,
                                                float* __restrict__ dinv) {
  __shared__ int ldeg[1024];
  __shared__ int s[1024];
  int b = blockIdx.x;
  int t = threadIdx.x;
  int w = t >> 6, lane = t & 63;
  int gid = (b << CSH) + t;
  ldeg[t] = 0;
  __syncthreads();
  for (int blk = w; blk < PBLK; blk += 16) {
    int c = cnt[blk * NCB + b];
    const unsigned* p = stg + ((size_t)blk * NCB + b) * SCAP;
    for (int e = lane; e < c; e += 64) atomicAdd(&ldeg[p[e] >> 17], 1);
  }
  __syncthreads();
  int v = ldeg[t];
  if (gid < NN) dinv[gid] = rsqrtf((float)(v + 1));  // +1 self-loop
  s[t] = v;
  __syncthreads();
  for (int off = 1; off < 1024; off <<= 1) {
    int u = (t >= off) ? s[t - off] : 0;
    __syncthreads();
    if (t >= off) s[t] += u;
    __syncthreads();
  }
  if (gid < NN) rows[gid] = s[t] - v;       // bucket-local exclusive
  if (t == 1023) part[b] = s[t];            // bucket total
}

__global__ void k_scan_part(const int* __restrict__ part, int* __restrict__ offs) {
  __shared__ int s[128];
  int t = threadIdx.x;
  int v = (t < NCB) ? part[t] : 0;
  s[t] = v;
  __syncthreads();
  for (int off = 1; off < 128; off <<= 1) {
    int u = (t >= off) ? s[t - off] : 0;
    __syncthreads();
    if (t >= off) s[t] += u;
    __syncthreads();
  }
  if (t < NCB) offs[t] = s[t] - v;
}

// globalize rows + fused batch-starts.
__global__ void k_scan_add(int* __restrict__ rows, const int* __restrict__ offs,
                           const int* __restrict__ batch, int* __restrict__ start) {
  int i = blockIdx.x * 256 + threadIdx.x;
  if (i >= NN) return;
  rows[i] += offs[i >> 10];
  if (i == 0) rows[NN] = EE;
  int b = batch[i];
  int prev = (i == 0) ? -1 : batch[i - 1];
  for (int g = prev + 1; g <= b; ++g) start[g] = i;
  if (i == NN - 1)
    for (int g = b + 1; g <= NG; ++g) start[g] = NN;
}

// Per bucket: place srcs via LDS cursors into the bucket's exclusive CSR segment.
__global__ __launch_bounds__(1024) void k_place(const unsigned* __restrict__ stg,
                                                const int* __restrict__ cnt,
                                                const int* __restrict__ rows,
                                                int* __restrict__ csr) {
  __shared__ int lrow[1024];
  __shared__ int lcur[1024];
  int b = blockIdx.x;
  int t = threadIdx.x;
  int w = t >> 6, lane = t & 63;
  int gid = (b << CSH) + t;
  lrow[t] = (gid < NN) ? rows[gid] : 0;
  lcur[t] = 0;
  __syncthreads();
  for (int blk = w; blk < PBLK; blk += 16) {
    int c = cnt[blk * NCB + b];
    const unsigned* p = stg + ((size_t)blk * NCB + b) * SCAP;
    for (int e = lane; e < c; e += 64) {
      unsigned x = p[e];
      int ld = x >> 17;
      int q = atomicAdd(&lcur[ld], 1);
      csr[lrow[ld] + q] = (int)(x & 0x1FFFFu);
    }
  }
}

// Hs(bf16) = diag(dinv) * (X @ W).  64-row tile, 256 threads, 4x8 register tile.
__global__ __launch_bounds__(256) void k_gemm_scale(
    const float* __restrict__ X, const float* __restrict__ W,
    const float* __restrict__ dinv, unsigned short* __restrict__ Hs) {
  __shared__ float Xs[64][36];
  __shared__ float Ws[32][128];
  const int t = threadIdx.x;
  const int tx = t & 15;
  const int ty = t >> 4;
  const int row0 = blockIdx.x * 64;
  float acc[4][8];
#pragma unroll
  for (int i = 0; i < 4; ++i)
#pragma unroll
    for (int j = 0; j < 8; ++j) acc[i][j] = 0.f;

  const int lr = t >> 2;
  const int lk = (t & 3) * 8;
  const int wk = t >> 5;
  const int wc = (t & 31) * 4;

  for (int kc = 0; kc < 128; kc += 32) {
    if (row0 + lr < NN) {
      const float* xp = X + (size_t)(row0 + lr) * CH + kc + lk;
      *(float4*)&Xs[lr][lk] = *(const float4*)xp;
      *(float4*)&Xs[lr][lk + 4] = *(const float4*)(xp + 4);
    } else {
      float4 z = {0.f, 0.f, 0.f, 0.f};
      *(float4*)&Xs[lr][lk] = z;
      *(float4*)&Xs[lr][lk + 4] = z;
    }
#pragma unroll
    for (int i = 0; i < 4; ++i)
      *(float4*)&Ws[wk + 8 * i][wc] =
          *(const float4*)(W + (size_t)(kc + wk + 8 * i) * CH + wc);
    __syncthreads();
#pragma unroll
    for (int k = 0; k < 32; ++k) {
      float4 w0 = *(float4*)&Ws[k][tx * 8];
      float4 w1 = *(float4*)&Ws[k][tx * 8 + 4];
#pragma unroll
      for (int i = 0; i < 4; ++i) {
        float xv = Xs[ty * 4 + i][k];
        acc[i][0] += xv * w0.x; acc[i][1] += xv * w0.y;
        acc[i][2] += xv * w0.z; acc[i][3] += xv * w0.w;
        acc[i][4] += xv * w1.x; acc[i][5] += xv * w1.y;
        acc[i][6] += xv * w1.z; acc[i][7] += xv * w1.w;
      }
    }
    __syncthreads();
  }
#pragma unroll
  for (int i = 0; i < 4; ++i) {
    int r = row0 + ty * 4 + i;
    if (r < NN) {
      float d = dinv[r];
      uint4 u;
      u.x = pack2(d * acc[i][0], d * acc[i][1]);
      u.y = pack2(d * acc[i][2], d * acc[i][3]);
      u.z = pack2(d * acc[i][4], d * acc[i][5]);
      u.w = pack2(d * acc[i][6], d * acc[i][7]);
      *(uint4*)&Hs[(size_t)r * CH + tx * 8] = u;
    }
  }
}

// out[i] = relu(dinv[i]*(Hs[i] + sum_{e:dst=i} Hs[csr[e]]) + b). One wave per node.
__global__ __launch_bounds__(256) void k_aggregate(
    const unsigned* __restrict__ H, const int* __restrict__ rows,
    const int* __restrict__ csr, const float* __restrict__ dinv,
    const float* __restrict__ bias, float* __restrict__ out) {
  int node = blockIdx.x * 4 + (threadIdx.x >> 6);
  int lane = threadIdx.x & 63;
  if (node >= NN) return;
  float bx = bias[2 * lane], by = bias[2 * lane + 1];
  unsigned sv = H[(size_t)node * 64 + lane];  // self-loop term
  float ax = bflo(sv), ay = bfhi(sv);
  int e = rows[node], e1 = rows[node + 1];
  for (; e + 8 <= e1; e += 8) {
    int j0 = csr[e],     j1 = csr[e + 1], j2 = csr[e + 2], j3 = csr[e + 3];
    int j4 = csr[e + 4], j5 = csr[e + 5], j6 = csr[e + 6], j7 = csr[e + 7];
    unsigned v0 = H[(size_t)j0 * 64 + lane];
    unsigned v1 = H[(size_t)j1 * 64 + lane];
    unsigned v2 = H[(size_t)j2 * 64 + lane];
    unsigned v3 = H[(size_t)j3 * 64 + lane];
    unsigned v4 = H[(size_t)j4 * 64 + lane];
    unsigned v5 = H[(size_t)j5 * 64 + lane];
    unsigned v6 = H[(size_t)j6 * 64 + lane];
    unsigned v7 = H[(size_t)j7 * 64 + lane];
    ax += ((bflo(v0) + bflo(v1)) + (bflo(v2) + bflo(v3))) +
          ((bflo(v4) + bflo(v5)) + (bflo(v6) + bflo(v7)));
    ay += ((bfhi(v0) + bfhi(v1)) + (bfhi(v2) + bfhi(v3))) +
          ((bfhi(v4) + bfhi(v5)) + (bfhi(v6) + bfhi(v7)));
  }
  if (e + 4 <= e1) {
    int j0 = csr[e], j1 = csr[e + 1], j2 = csr[e + 2], j3 = csr[e + 3];
    unsigned v0 = H[(size_t)j0 * 64 + lane];
    unsigned v1 = H[(size_t)j1 * 64 + lane];
    unsigned v2 = H[(size_t)j2 * 64 + lane];
    unsigned v3 = H[(size_t)j3 * 64 + lane];
    ax += (bflo(v0) + bflo(v1)) + (bflo(v2) + bflo(v3));
    ay += (bfhi(v0) + bfhi(v1)) + (bfhi(v2) + bfhi(v3));
    e += 4;
  }
  for (; e < e1; ++e) {
    unsigned v = H[(size_t)csr[e] * 64 + lane];
    ax += bflo(v);
    ay += bfhi(v);
  }
  float d = dinv[node];
  float2 o;
  o.x = fmaxf(fmaf(d, ax, bx), 0.f);
  o.y = fmaxf(fmaf(d, ay, by), 0.f);
  ((float2*)out)[(size_t)node * 64 + lane] = o;
}

// one block (2 waves) per graph: segmented mean, no atomics.
__global__ __launch_bounds__(256) void k_pool_mean(
    const float* __restrict__ A, const int* __restrict__ start,
    float* __restrict__ pooled) {
  __shared__ float part[128];
  int g = blockIdx.x;
  int c = threadIdx.x & 127;
  int half = threadIdx.x >> 7;
  int s0 = start[g], s1 = start[g + 1];
  float sum = 0.f;
  for (int i = s0 + half; i < s1; i += 2)
    sum += A[(size_t)i * CH + c];
  if (half) part[c] = sum;
  __syncthreads();
  if (!half) {
    sum += part[c];
    float n = fmaxf((float)(s1 - s0), 1.0f);
    pooled[(size_t)g * CH + c] = sum / n;
  }
}

__global__ void k_head1(const float* __restrict__ pooled,
                        const float* __restrict__ W3, const float* __restrict__ b3,
                        float* __restrict__ g1) {
  __shared__ float row[128];
  int g = blockIdx.x, c = threadIdx.x;
  row[c] = pooled[(size_t)g * CH + c];
  __syncthreads();
  float acc = b3[c];
  for (int k = 0; k < 128; ++k) acc += row[k] * W3[(size_t)k * CH + c];
  g1[(size_t)g * CH + c] = fmaxf(acc, 0.f);
}

__global__ void k_head2(const float* __restrict__ g1, const float* __restrict__ W4,
                        const float* __restrict__ b4, float* __restrict__ out) {
  __shared__ float row[128];
  int g = blockIdx.x, c = threadIdx.x;  // 64 threads
  row[c] = g1[(size_t)g * CH + c];
  row[c + 64] = g1[(size_t)g * CH + c + 64];
  __syncthreads();
  float acc = b4[c];
  for (int k = 0; k < 128; ++k) acc += row[k] * W4[(size_t)k * OC + c];
  out[(size_t)g * OC + c] = acc;
}

extern "C" void kernel_launch(void* const* d_in, const int* in_sizes, int n_in,
                              void* d_out, int out_size, void* d_ws, size_t ws_size,
                              hipStream_t stream) {
  const float* X   = (const float*)d_in[0];
  const int* ei    = (const int*)d_in[1];
  const int* batch = (const int*)d_in[2];
  const float* W1  = (const float*)d_in[3];
  const float* b1  = (const float*)d_in[4];
  const float* W2  = (const float*)d_in[5];
  const float* b2  = (const float*)d_in[6];
  const float* W3  = (const float*)d_in[7];
  const float* b3  = (const float*)d_in[8];
  const float* W4  = (const float*)d_in[9];
  const float* b4  = (const float*)d_in[10];
  float* out = (float*)d_out;
  float* ws = (float*)d_ws;

  const int* src = ei;        // edge_index[0]
  const int* dst = ei + EE;   // edge_index[1]

  float* dinv = ws + O_DINV;
  int* rows   = (int*)(ws + O_ROWS);
  int* cnt    = (int*)(ws + O_CNT);
  int* part   = (int*)(ws + O_PART);
  int* offs   = (int*)(ws + O_OFFS);
  int* csr    = (int*)(ws + O_CSR);
  unsigned short* Hs = (unsigned short*)(ws + O_HS);
  unsigned* stg = (unsigned*)(ws + O_STG);
  float* A1   = ws + O_A1;
  int* start  = (int*)(ws + O_START);
  float* pool = ws + O_POOL;
  float* g1   = ws + O_G1;

  k_part<<<PBLK, 1024, 0, stream>>>(src, dst, cnt, stg);
  k_count<<<NCB, 1024, 0, stream>>>(stg, cnt, rows, part, dinv);
  k_scan_part<<<1, 128, 0, stream>>>(part, offs);
  k_scan_add<<<(NN + 255) / 256, 256, 0, stream>>>(rows, offs, batch, start);
  k_place<<<NCB, 1024, 0, stream>>>(stg, cnt, rows, csr);

  // layer 1
  k_gemm_scale<<<(NN + 63) / 64, 256, 0, stream>>>(X, W1, dinv, Hs);
  k_aggregate<<<(NN + 3) / 4, 256, 0, stream>>>((const unsigned*)Hs, rows, csr, dinv, b1, A1);
  // layer 2
  k_gemm_scale<<<(NN + 63) / 64, 256, 0, stream>>>(A1, W2, dinv, Hs);
  k_aggregate<<<(NN + 3) / 4, 256, 0, stream>>>((const unsigned*)Hs, rows, csr, dinv, b2, A1);

  k_pool_mean<<<NG, 256, 0, stream>>>(A1, start, pool);
  k_head1<<<NG, 128, 0, stream>>>(pool, W3, b3, g1);
  k_head2<<<NG, 64, 0, stream>>>(g1, W4, b4, out);
}

// Round 10
// 422.276 us; speedup vs baseline: 2.0377x; 1.0350x over previous
//
#include <hip/hip_runtime.h>

#define NN 100000
#define EE 1600000
#define CH 128
#define NG 512
#define OC 64

// coarse radix partition: 98 buckets of 1024 nodes; fixed-capacity staging cells
#define CSH 10
#define NCB 98
#define PBLK 256
#define PCHUNK 6250     // 256*6250 = 1.6M exactly
#define SCAP 128        // per (block,bucket) cell: mean 63.8 + 8 sigma

// workspace element offsets (4-byte units)
#define O_DINV   0
#define O_ROWS   200128
#define O_CNT    300160   // 256*98 = 25088 per-cell counts
#define O_PART   400192
#define O_OFFS   400320
#define O_CSR    400448
#define O_HS     2000448  // bf16 Hs: NN*CH ushorts = 6.4M words (ends 8400448)
#define O_STG    8400448  // staging 256*98*128 = 3.21M words
#define O_WT1    8400448  // split W1: hi+lo = 32768 ushorts = 16384 words (dead stg)
#define O_WT2    8416832  // = O_WT1 + 16384 words (r9 bug: overlapped wt1's lo half)
#define O_A1     14800448
#define O_START  27600448
#define O_POOL   27601024
#define O_G1     27666560

typedef __attribute__((ext_vector_type(8))) short short8v;
typedef __attribute__((ext_vector_type(4))) float float4v;

static __device__ __forceinline__ unsigned short f2bf(float x) {
  unsigned u = __float_as_uint(x);
  return (unsigned short)((u + 0x7FFFu + ((u >> 16) & 1u)) >> 16);  // RNE
}
static __device__ __forceinline__ float bf2f(unsigned short h) {
  return __uint_as_float((unsigned)h << 16);
}
static __device__ __forceinline__ float bflo(unsigned v) {
  return __uint_as_float(v << 16);
}
static __device__ __forceinline__ float bfhi(unsigned v) {
  return __uint_as_float(v & 0xFFFF0000u);
}

// LDS radix scatter: hist -> scan -> ordered LDS buffer -> contiguous run copies.
__global__ __launch_bounds__(1024) void k_part(const int* __restrict__ src,
                                               const int* __restrict__ dst,
                                               int* __restrict__ cnt,
                                               unsigned* __restrict__ stg) {
  __shared__ int hist[NCB];   // counts, then exclusive bases
  __shared__ int lcur[NCB];
  __shared__ unsigned lout[PCHUNK];
  int t = threadIdx.x;
  int e0 = blockIdx.x * PCHUNK;
  if (t < NCB) { hist[t] = 0; lcur[t] = 0; }
  __syncthreads();
  for (int e = e0 + t; e < e0 + PCHUNK; e += 1024)
    atomicAdd(&hist[dst[e] >> CSH], 1);
  __syncthreads();
  if (t == 0) {
    int s = 0;
    for (int i = 0; i < NCB; ++i) { int v = hist[i]; hist[i] = s; s += v; }
  }
  __syncthreads();
  for (int e = e0 + t; e < e0 + PCHUNK; e += 1024) {
    int d = dst[e];
    int b = d >> CSH;
    int p = hist[b] + atomicAdd(&lcur[b], 1);
    lout[p] = (unsigned)src[e] | ((unsigned)(d & 1023) << 17);
  }
  __syncthreads();
  int w = t >> 6, lane = t & 63;
  unsigned* mystg = stg + (size_t)blockIdx.x * NCB * SCAP;
  for (int b = w; b < NCB; b += 16) {
    int beg = hist[b];
    int end = (b == NCB - 1) ? PCHUNK : hist[b + 1];
    int n = min(end - beg, SCAP);
    for (int i = lane; i < n; i += 64) mystg[b * SCAP + i] = lout[beg + i];
    if (lane == 0) cnt[blockIdx.x * NCB + b] = n;
  }
}

// Per bucket: local degree histogram from staging, fused dinv + local scan.
__global__ __launch_bounds__(1024) void k_count(const unsigned* __restrict__ stg,
                                                const int* __restrict__ cnt,
                                                int* __restrict__ rows,
                                                int* __restrict__ part,
                                                float* __restrict__ dinv) {
  __shared__ int ldeg[1024];
  __shared__ int s[1024];
  int b = blockIdx.x;
  int t = threadIdx.x;
  int w = t >> 6, lane = t & 63;
  int gid = (b << CSH) + t;
  ldeg[t] = 0;
  __syncthreads();
  for (int blk = w; blk < PBLK; blk += 16) {
    int c = cnt[blk * NCB + b];
    const unsigned* p = stg + ((size_t)blk * NCB + b) * SCAP;
    for (int e = lane; e < c; e += 64) atomicAdd(&ldeg[p[e] >> 17], 1);
  }
  __syncthreads();
  int v = ldeg[t];
  if (gid < NN) dinv[gid] = rsqrtf((float)(v + 1));  // +1 self-loop
  s[t] = v;
  __syncthreads();
  for (int off = 1; off < 1024; off <<= 1) {
    int u = (t >= off) ? s[t - off] : 0;
    __syncthreads();
    if (t >= off) s[t] += u;
    __syncthreads();
  }
  if (gid < NN) rows[gid] = s[t] - v;       // bucket-local exclusive
  if (t == 1023) part[b] = s[t];            // bucket total
}

__global__ void k_scan_part(const int* __restrict__ part, int* __restrict__ offs) {
  __shared__ int s[128];
  int t = threadIdx.x;
  int v = (t < NCB) ? part[t] : 0;
  s[t] = v;
  __syncthreads();
  for (int off = 1; off < 128; off <<= 1) {
    int u = (t >= off) ? s[t - off] : 0;
    __syncthreads();
    if (t >= off) s[t] += u;
    __syncthreads();
  }
  if (t < NCB) offs[t] = s[t] - v;
}

// globalize rows + fused batch-starts.
__global__ void k_scan_add(int* __restrict__ rows, const int* __restrict__ offs,
                           const int* __restrict__ batch, int* __restrict__ start) {
  int i = blockIdx.x * 256 + threadIdx.x;
  if (i >= NN) return;
  rows[i] += offs[i >> 10];
  if (i == 0) rows[NN] = EE;
  int b = batch[i];
  int prev = (i == 0) ? -1 : batch[i - 1];
  for (int g = prev + 1; g <= b; ++g) start[g] = i;
  if (i == NN - 1)
    for (int g = b + 1; g <= NG; ++g) start[g] = NN;
}

// Per bucket: place srcs via LDS cursors into the bucket's exclusive CSR segment.
__global__ __launch_bounds__(1024) void k_place(const unsigned* __restrict__ stg,
                                                const int* __restrict__ cnt,
                                                const int* __restrict__ rows,
                                                int* __restrict__ csr) {
  __shared__ int lrow[1024];
  __shared__ int lcur[1024];
  int b = blockIdx.x;
  int t = threadIdx.x;
  int w = t >> 6, lane = t & 63;
  int gid = (b << CSH) + t;
  lrow[t] = (gid < NN) ? rows[gid] : 0;
  lcur[t] = 0;
  __syncthreads();
  for (int blk = w; blk < PBLK; blk += 16) {
    int c = cnt[blk * NCB + b];
    const unsigned* p = stg + ((size_t)blk * NCB + b) * SCAP;
    for (int e = lane; e < c; e += 64) {
      unsigned x = p[e];
      int ld = x >> 17;
      int q = atomicAdd(&lcur[ld], 1);
      csr[lrow[ld] + q] = (int)(x & 0x1FFFFu);
    }
  }
}

// split W (fp32 [k][n]) into bf16 hi/lo, transposed to [n][k] for B-fragments.
__global__ void k_wsplit(const float* __restrict__ W,
                         unsigned short* __restrict__ wth,
                         unsigned short* __restrict__ wtl) {
  int id = blockIdx.x * 256 + threadIdx.x;   // 16384
  int k = id >> 7, n = id & 127;
  float w = W[id];
  unsigned short h = f2bf(w);
  unsigned short l = f2bf(w - bf2f(h));
  wth[n * 128 + k] = h;
  wtl[n * 128 + k] = l;
}

// Hs(bf16) = diag(dinv) * (X @ W) via split-bf16 MFMA (XhWh + XhWl + XlWh).
// Block: 128 rows x 64 cols, 256 threads (4 waves, each 32 rows x 64 cols).
__global__ __launch_bounds__(256) void k_gemm_mfma(
    const float* __restrict__ X, const unsigned short* __restrict__ wth,
    const unsigned short* __restrict__ wtl, const float* __restrict__ dinv,
    unsigned short* __restrict__ Hs) {
  __shared__ __align__(16) unsigned short sWh[64 * 136];  // [n][k] pad 136
  __shared__ __align__(16) unsigned short sWl[64 * 136];
  __shared__ __align__(16) unsigned short sXh[128 * 40];  // [row][k-chunk 32] pad 40
  __shared__ __align__(16) unsigned short sXl[128 * 40];

  const int t = threadIdx.x;
  const int w = t >> 6, lane = t & 63;
  const int quad = lane >> 4, lr = lane & 15;
  const int row0 = blockIdx.x * 128;
  const int col0 = blockIdx.y * 64;

  // stage W halves (once): 64 n-rows x 128 k bf16, hi & lo
#pragma unroll
  for (int j = 0; j < 8; ++j) {
    int id = t + j * 256;            // 2048 ushort4 per array
    int n = id >> 5, kk = (id & 31) * 4;
    *(ushort4*)&sWh[n * 136 + kk] = *(const ushort4*)&wth[(col0 + n) * 128 + kk];
    *(ushort4*)&sWl[n * 136 + kk] = *(const ushort4*)&wtl[(col0 + n) * 128 + kk];
  }

  float4v acc[2][4];
#pragma unroll
  for (int mi = 0; mi < 2; ++mi)
#pragma unroll
    for (int ni = 0; ni < 4; ++ni) acc[mi][ni] = (float4v){0.f, 0.f, 0.f, 0.f};

  for (int ks = 0; ks < 4; ++ks) {
    const int k0 = ks * 32;
    if (ks) __syncthreads();  // protect previous compute before X overwrite
    // stage X[row0..row0+127][k0..k0+31] as bf16 hi/lo
#pragma unroll
    for (int i = 0; i < 4; ++i) {
      int row = i * 32 + (t >> 3);
      int seg = t & 7;
      int gr = row0 + row;
      float4 xv = {0.f, 0.f, 0.f, 0.f};
      if (gr < NN) xv = *(const float4*)&X[(size_t)gr * CH + k0 + seg * 4];
      ushort4 h, l;
      h.x = f2bf(xv.x); l.x = f2bf(xv.x - bf2f(h.x));
      h.y = f2bf(xv.y); l.y = f2bf(xv.y - bf2f(h.y));
      h.z = f2bf(xv.z); l.z = f2bf(xv.z - bf2f(h.z));
      h.w = f2bf(xv.w); l.w = f2bf(xv.w - bf2f(h.w));
      *(ushort4*)&sXh[row * 40 + seg * 4] = h;
      *(ushort4*)&sXl[row * 40 + seg * 4] = l;
    }
    __syncthreads();  // also covers the one-time W staging before first use

    short8v ah[2], al[2];
#pragma unroll
    for (int mi = 0; mi < 2; ++mi) {
      int r = w * 32 + mi * 16 + lr;
      ah[mi] = *(const short8v*)&sXh[r * 40 + quad * 8];
      al[mi] = *(const short8v*)&sXl[r * 40 + quad * 8];
    }
#pragma unroll
    for (int ni = 0; ni < 4; ++ni) {
      int n = ni * 16 + lr;
      short8v bh = *(const short8v*)&sWh[n * 136 + k0 + quad * 8];
      short8v bl = *(const short8v*)&sWl[n * 136 + k0 + quad * 8];
#pragma unroll
      for (int mi = 0; mi < 2; ++mi) {
        acc[mi][ni] = __builtin_amdgcn_mfma_f32_16x16x32_bf16(ah[mi], bh, acc[mi][ni], 0, 0, 0);
        acc[mi][ni] = __builtin_amdgcn_mfma_f32_16x16x32_bf16(ah[mi], bl, acc[mi][ni], 0, 0, 0);
        acc[mi][ni] = __builtin_amdgcn_mfma_f32_16x16x32_bf16(al[mi], bh, acc[mi][ni], 0, 0, 0);
      }
    }
  }

  // epilogue: D[row=quad*4+r][col=lr] per tile; scale by dinv, pack bf16
#pragma unroll
  for (int mi = 0; mi < 2; ++mi) {
#pragma unroll
    for (int r = 0; r < 4; ++r) {
      int grow = row0 + w * 32 + mi * 16 + quad * 4 + r;
      if (grow < NN) {
        float d = dinv[grow];
#pragma unroll
        for (int ni = 0; ni < 4; ++ni)
          Hs[(size_t)grow * CH + col0 + ni * 16 + lr] = f2bf(d * acc[mi][ni][r]);
      }
    }
  }
}

// out[i] = relu(dinv[i]*(Hs[i] + sum_{e:dst=i} Hs[csr[e]]) + b). One wave per node.
__global__ __launch_bounds__(256) void k_aggregate(
    const unsigned* __restrict__ H, const int* __restrict__ rows,
    const int* __restrict__ csr, const float* __restrict__ dinv,
    const float* __restrict__ bias, float* __restrict__ out) {
  int node = blockIdx.x * 4 + (threadIdx.x >> 6);
  int lane = threadIdx.x & 63;
  if (node >= NN) return;
  float bx = bias[2 * lane], by = bias[2 * lane + 1];
  unsigned sv = H[(size_t)node * 64 + lane];  // self-loop term
  float ax = bflo(sv), ay = bfhi(sv);
  int e = rows[node], e1 = rows[node + 1];
  for (; e + 8 <= e1; e += 8) {
    int j0 = csr[e],     j1 = csr[e + 1], j2 = csr[e + 2], j3 = csr[e + 3];
    int j4 = csr[e + 4], j5 = csr[e + 5], j6 = csr[e + 6], j7 = csr[e + 7];
    unsigned v0 = H[(size_t)j0 * 64 + lane];
    unsigned v1 = H[(size_t)j1 * 64 + lane];
    unsigned v2 = H[(size_t)j2 * 64 + lane];
    unsigned v3 = H[(size_t)j3 * 64 + lane];
    unsigned v4 = H[(size_t)j4 * 64 + lane];
    unsigned v5 = H[(size_t)j5 * 64 + lane];
    unsigned v6 = H[(size_t)j6 * 64 + lane];
    unsigned v7 = H[(size_t)j7 * 64 + lane];
    ax += ((bflo(v0) + bflo(v1)) + (bflo(v2) + bflo(v3))) +
          ((bflo(v4) + bflo(v5)) + (bflo(v6) + bflo(v7)));
    ay += ((bfhi(v0) + bfhi(v1)) + (bfhi(v2) + bfhi(v3))) +
          ((bfhi(v4) + bfhi(v5)) + (bfhi(v6) + bfhi(v7)));
  }
  if (e + 4 <= e1) {
    int j0 = csr[e], j1 = csr[e + 1], j2 = csr[e + 2], j3 = csr[e + 3];
    unsigned v0 = H[(size_t)j0 * 64 + lane];
    unsigned v1 = H[(size_t)j1 * 64 + lane];
    unsigned v2 = H[(size_t)j2 * 64 + lane];
    unsigned v3 = H[(size_t)j3 * 64 + lane];
    ax += (bflo(v0) + bflo(v1)) + (bflo(v2) + bflo(v3));
    ay += (bfhi(v0) + bfhi(v1)) + (bfhi(v2) + bfhi(v3));
    e += 4;
  }
  for (; e < e1; ++e) {
    unsigned v = H[(size_t)csr[e] * 64 + lane];
    ax += bflo(v);
    ay += bfhi(v);
  }
  float d = dinv[node];
  float2 o;
  o.x = fmaxf(fmaf(d, ax, bx), 0.f);
  o.y = fmaxf(fmaf(d, ay, by), 0.f);
  ((float2*)out)[(size_t)node * 64 + lane] = o;
}

// one block (2 waves) per graph: segmented mean, no atomics.
__global__ __launch_bounds__(256) void k_pool_mean(
    const float* __restrict__ A, const int* __restrict__ start,
    float* __restrict__ pooled) {
  __shared__ float part[128];
  int g = blockIdx.x;
  int c = threadIdx.x & 127;
  int half = threadIdx.x >> 7;
  int s0 = start[g], s1 = start[g + 1];
  float sum = 0.f;
  for (int i = s0 + half; i < s1; i += 2)
    sum += A[(size_t)i * CH + c];
  if (half) part[c] = sum;
  __syncthreads();
  if (!half) {
    sum += part[c];
    float n = fmaxf((float)(s1 - s0), 1.0f);
    pooled[(size_t)g * CH + c] = sum / n;
  }
}

__global__ void k_head1(const float* __restrict__ pooled,
                        const float* __restrict__ W3, const float* __restrict__ b3,
                        float* __restrict__ g1) {
  __shared__ float row[128];
  int g = blockIdx.x, c = threadIdx.x;
  row[c] = pooled[(size_t)g * CH + c];
  __syncthreads();
  float acc = b3[c];
  for (int k = 0; k < 128; ++k) acc += row[k] * W3[(size_t)k * CH + c];
  g1[(size_t)g * CH + c] = fmaxf(acc, 0.f);
}

__global__ void k_head2(const float* __restrict__ g1, const float* __restrict__ W4,
                        const float* __restrict__ b4, float* __restrict__ out) {
  __shared__ float row[128];
  int g = blockIdx.x, c = threadIdx.x;  // 64 threads
  row[c] = g1[(size_t)g * CH + c];
  row[c + 64] = g1[(size_t)g * CH + c + 64];
  __syncthreads();
  float acc = b4[c];
  for (int k = 0; k < 128; ++k) acc += row[k] * W4[(size_t)k * OC + c];
  out[(size_t)g * OC + c] = acc;
}

extern "C" void kernel_launch(void* const* d_in, const int* in_sizes, int n_in,
                              void* d_out, int out_size, void* d_ws, size_t ws_size,
                              hipStream_t stream) {
  const float* X   = (const float*)d_in[0];
  const int* ei    = (const int*)d_in[1];
  const int* batch = (const int*)d_in[2];
  const float* W1  = (const float*)d_in[3];
  const float* b1  = (const float*)d_in[4];
  const float* W2  = (const float*)d_in[5];
  const float* b2  = (const float*)d_in[6];
  const float* W3  = (const float*)d_in[7];
  const float* b3  = (const float*)d_in[8];
  const float* W4  = (const float*)d_in[9];
  const float* b4  = (const float*)d_in[10];
  float* out = (float*)d_out;
  float* ws = (float*)d_ws;

  const int* src = ei;        // edge_index[0]
  const int* dst = ei + EE;   // edge_index[1]

  float* dinv = ws + O_DINV;
  int* rows   = (int*)(ws + O_ROWS);
  int* cnt    = (int*)(ws + O_CNT);
  int* part   = (int*)(ws + O_PART);
  int* offs   = (int*)(ws + O_OFFS);
  int* csr    = (int*)(ws + O_CSR);
  unsigned short* Hs = (unsigned short*)(ws + O_HS);
  unsigned* stg = (unsigned*)(ws + O_STG);
  unsigned short* wt1 = (unsigned short*)(ws + O_WT1);
  unsigned short* wt2 = (unsigned short*)(ws + O_WT2);
  float* A1   = ws + O_A1;
  int* start  = (int*)(ws + O_START);
  float* pool = ws + O_POOL;
  float* g1   = ws + O_G1;

  k_part<<<PBLK, 1024, 0, stream>>>(src, dst, cnt, stg);
  k_count<<<NCB, 1024, 0, stream>>>(stg, cnt, rows, part, dinv);
  k_scan_part<<<1, 128, 0, stream>>>(part, offs);
  k_scan_add<<<(NN + 255) / 256, 256, 0, stream>>>(rows, offs, batch, start);
  k_place<<<NCB, 1024, 0, stream>>>(stg, cnt, rows, csr);
  // after k_place the staging region is dead; wt1/wt2 overwrite its start
  k_wsplit<<<64, 256, 0, stream>>>(W1, wt1, wt1 + 16384);
  k_wsplit<<<64, 256, 0, stream>>>(W2, wt2, wt2 + 16384);

  dim3 ggrid((NN + 127) / 128, 2);
  // layer 1
  k_gemm_mfma<<<ggrid, 256, 0, stream>>>(X, wt1, wt1 + 16384, dinv, Hs);
  k_aggregate<<<(NN + 3) / 4, 256, 0, stream>>>((const unsigned*)Hs, rows, csr, dinv, b1, A1);
  // layer 2
  k_gemm_mfma<<<ggrid, 256, 0, stream>>>(A1, wt2, wt2 + 16384, dinv, Hs);
  k_aggregate<<<(NN + 3) / 4, 256, 0, stream>>>((const unsigned*)Hs, rows, csr, dinv, b2, A1);

  k_pool_mean<<<NG, 256, 0, stream>>>(A1, start, pool);
  k_head1<<<NG, 128, 0, stream>>>(pool, W3, b3, g1);
  k_head2<<<NG, 64, 0, stream>>>(g1, W4, b4, out);
}

// Round 11
// 404.133 us; speedup vs baseline: 2.1292x; 1.0449x over previous
//
#include <hip/hip_runtime.h>

#define NN 100000
#define EE 1600000
#define CH 128
#define NG 512
#define OC 64

// coarse radix partition: 98 buckets of 1024 nodes; fixed-capacity staging cells
#define CSH 10
#define NCB 98
#define PBLK 256
#define PCHUNK 6250     // 256*6250 = 1.6M exactly
#define SCAP 128        // per (block,bucket) cell: mean 63.8 + 8 sigma

// workspace element offsets (4-byte units)
#define O_DINV   0
#define O_ROWS   200128
#define O_CNT    300160   // 256*98 = 25088 per-cell counts
#define O_PART   400192
#define O_OFFS   400320
#define O_CSR    400448
#define O_HS     2000448  // bf16 Hs: NN*CH ushorts = 6.4M words (ends 8400448)
#define O_STG    8400448  // staging 256*98*128 = 3.21M words
#define O_WT1    8400448  // split W1: hi+lo = 32768 ushorts = 16384 words (dead stg)
#define O_WT2    8416832  // = O_WT1 + 16384 words
#define O_A1     14800448
#define O_START  27600448

typedef __attribute__((ext_vector_type(8))) short short8v;
typedef __attribute__((ext_vector_type(4))) float float4v;

static __device__ __forceinline__ unsigned short f2bf(float x) {
  unsigned u = __float_as_uint(x);
  return (unsigned short)((u + 0x7FFFu + ((u >> 16) & 1u)) >> 16);  // RNE
}
static __device__ __forceinline__ float bf2f(unsigned short h) {
  return __uint_as_float((unsigned)h << 16);
}
static __device__ __forceinline__ float bflo(unsigned v) {
  return __uint_as_float(v << 16);
}
static __device__ __forceinline__ float bfhi(unsigned v) {
  return __uint_as_float(v & 0xFFFF0000u);
}

// LDS radix scatter: hist -> scan -> ordered LDS buffer -> contiguous run copies.
__global__ __launch_bounds__(1024) void k_part(const int* __restrict__ src,
                                               const int* __restrict__ dst,
                                               int* __restrict__ cnt,
                                               unsigned* __restrict__ stg) {
  __shared__ int hist[NCB];   // counts, then exclusive bases
  __shared__ int lcur[NCB];
  __shared__ unsigned lout[PCHUNK];
  int t = threadIdx.x;
  int e0 = blockIdx.x * PCHUNK;
  if (t < NCB) { hist[t] = 0; lcur[t] = 0; }
  __syncthreads();
  for (int e = e0 + t; e < e0 + PCHUNK; e += 1024)
    atomicAdd(&hist[dst[e] >> CSH], 1);
  __syncthreads();
  if (t == 0) {
    int s = 0;
    for (int i = 0; i < NCB; ++i) { int v = hist[i]; hist[i] = s; s += v; }
  }
  __syncthreads();
  for (int e = e0 + t; e < e0 + PCHUNK; e += 1024) {
    int d = dst[e];
    int b = d >> CSH;
    int p = hist[b] + atomicAdd(&lcur[b], 1);
    lout[p] = (unsigned)src[e] | ((unsigned)(d & 1023) << 17);
  }
  __syncthreads();
  int w = t >> 6, lane = t & 63;
  unsigned* mystg = stg + (size_t)blockIdx.x * NCB * SCAP;
  for (int b = w; b < NCB; b += 16) {
    int beg = hist[b];
    int end = (b == NCB - 1) ? PCHUNK : hist[b + 1];
    int n = min(end - beg, SCAP);
    for (int i = lane; i < n; i += 64) mystg[b * SCAP + i] = lout[beg + i];
    if (lane == 0) cnt[blockIdx.x * NCB + b] = n;
  }
}

// Per bucket: local degree histogram from staging, fused dinv + local scan.
__global__ __launch_bounds__(1024) void k_count(const unsigned* __restrict__ stg,
                                                const int* __restrict__ cnt,
                                                int* __restrict__ rows,
                                                int* __restrict__ part,
                                                float* __restrict__ dinv) {
  __shared__ int ldeg[1024];
  __shared__ int s[1024];
  int b = blockIdx.x;
  int t = threadIdx.x;
  int w = t >> 6, lane = t & 63;
  int gid = (b << CSH) + t;
  ldeg[t] = 0;
  __syncthreads();
  for (int blk = w; blk < PBLK; blk += 16) {
    int c = cnt[blk * NCB + b];
    const unsigned* p = stg + ((size_t)blk * NCB + b) * SCAP;
    for (int e = lane; e < c; e += 64) atomicAdd(&ldeg[p[e] >> 17], 1);
  }
  __syncthreads();
  int v = ldeg[t];
  if (gid < NN) dinv[gid] = rsqrtf((float)(v + 1));  // +1 self-loop
  s[t] = v;
  __syncthreads();
  for (int off = 1; off < 1024; off <<= 1) {
    int u = (t >= off) ? s[t - off] : 0;
    __syncthreads();
    if (t >= off) s[t] += u;
    __syncthreads();
  }
  if (gid < NN) rows[gid] = s[t] - v;       // bucket-local exclusive
  if (t == 1023) part[b] = s[t];            // bucket total
}

__global__ void k_scan_part(const int* __restrict__ part, int* __restrict__ offs) {
  __shared__ int s[128];
  int t = threadIdx.x;
  int v = (t < NCB) ? part[t] : 0;
  s[t] = v;
  __syncthreads();
  for (int off = 1; off < 128; off <<= 1) {
    int u = (t >= off) ? s[t - off] : 0;
    __syncthreads();
    if (t >= off) s[t] += u;
    __syncthreads();
  }
  if (t < NCB) offs[t] = s[t] - v;
}

// globalize rows + fused batch-starts.
__global__ void k_scan_add(int* __restrict__ rows, const int* __restrict__ offs,
                           const int* __restrict__ batch, int* __restrict__ start) {
  int i = blockIdx.x * 256 + threadIdx.x;
  if (i >= NN) return;
  rows[i] += offs[i >> 10];
  if (i == 0) rows[NN] = EE;
  int b = batch[i];
  int prev = (i == 0) ? -1 : batch[i - 1];
  for (int g = prev + 1; g <= b; ++g) start[g] = i;
  if (i == NN - 1)
    for (int g = b + 1; g <= NG; ++g) start[g] = NN;
}

// Per bucket: place srcs via LDS cursors into the bucket's exclusive CSR segment.
__global__ __launch_bounds__(1024) void k_place(const unsigned* __restrict__ stg,
                                                const int* __restrict__ cnt,
                                                const int* __restrict__ rows,
                                                int* __restrict__ csr) {
  __shared__ int lrow[1024];
  __shared__ int lcur[1024];
  int b = blockIdx.x;
  int t = threadIdx.x;
  int w = t >> 6, lane = t & 63;
  int gid = (b << CSH) + t;
  lrow[t] = (gid < NN) ? rows[gid] : 0;
  lcur[t] = 0;
  __syncthreads();
  for (int blk = w; blk < PBLK; blk += 16) {
    int c = cnt[blk * NCB + b];
    const unsigned* p = stg + ((size_t)blk * NCB + b) * SCAP;
    for (int e = lane; e < c; e += 64) {
      unsigned x = p[e];
      int ld = x >> 17;
      int q = atomicAdd(&lcur[ld], 1);
      csr[lrow[ld] + q] = (int)(x & 0x1FFFFu);
    }
  }
}

// split W1,W2 (fp32 [k][n]) into bf16 hi/lo, transposed to [n][k]; one launch.
__global__ void k_wsplit(const float* __restrict__ W1, const float* __restrict__ W2,
                         unsigned short* __restrict__ wt1,
                         unsigned short* __restrict__ wt2) {
  int id = blockIdx.x * 256 + threadIdx.x;   // 32768
  const float* W = (id < 16384) ? W1 : W2;
  unsigned short* wt = (id < 16384) ? wt1 : wt2;
  int i = id & 16383;
  int k = i >> 7, n = i & 127;
  float w = W[i];
  unsigned short h = f2bf(w);
  unsigned short l = f2bf(w - bf2f(h));
  wt[n * 128 + k] = h;
  wt[16384 + n * 128 + k] = l;
}

// Hs(bf16) = diag(dinv) * (X @ W) via split-bf16 MFMA (XhWh + XhWl + XlWh).
__global__ __launch_bounds__(256) void k_gemm_mfma(
    const float* __restrict__ X, const unsigned short* __restrict__ wth,
    const unsigned short* __restrict__ wtl, const float* __restrict__ dinv,
    unsigned short* __restrict__ Hs) {
  __shared__ __align__(16) unsigned short sWh[64 * 136];  // [n][k] pad 136
  __shared__ __align__(16) unsigned short sWl[64 * 136];
  __shared__ __align__(16) unsigned short sXh[128 * 40];  // [row][k-chunk 32] pad 40
  __shared__ __align__(16) unsigned short sXl[128 * 40];

  const int t = threadIdx.x;
  const int w = t >> 6, lane = t & 63;
  const int quad = lane >> 4, lr = lane & 15;
  const int row0 = blockIdx.x * 128;
  const int col0 = blockIdx.y * 64;

#pragma unroll
  for (int j = 0; j < 8; ++j) {
    int id = t + j * 256;
    int n = id >> 5, kk = (id & 31) * 4;
    *(ushort4*)&sWh[n * 136 + kk] = *(const ushort4*)&wth[(col0 + n) * 128 + kk];
    *(ushort4*)&sWl[n * 136 + kk] = *(const ushort4*)&wtl[(col0 + n) * 128 + kk];
  }

  float4v acc[2][4];
#pragma unroll
  for (int mi = 0; mi < 2; ++mi)
#pragma unroll
    for (int ni = 0; ni < 4; ++ni) acc[mi][ni] = (float4v){0.f, 0.f, 0.f, 0.f};

  for (int ks = 0; ks < 4; ++ks) {
    const int k0 = ks * 32;
    if (ks) __syncthreads();
#pragma unroll
    for (int i = 0; i < 4; ++i) {
      int row = i * 32 + (t >> 3);
      int seg = t & 7;
      int gr = row0 + row;
      float4 xv = {0.f, 0.f, 0.f, 0.f};
      if (gr < NN) xv = *(const float4*)&X[(size_t)gr * CH + k0 + seg * 4];
      ushort4 h, l;
      h.x = f2bf(xv.x); l.x = f2bf(xv.x - bf2f(h.x));
      h.y = f2bf(xv.y); l.y = f2bf(xv.y - bf2f(h.y));
      h.z = f2bf(xv.z); l.z = f2bf(xv.z - bf2f(h.z));
      h.w = f2bf(xv.w); l.w = f2bf(xv.w - bf2f(h.w));
      *(ushort4*)&sXh[row * 40 + seg * 4] = h;
      *(ushort4*)&sXl[row * 40 + seg * 4] = l;
    }
    __syncthreads();

    short8v ah[2], al[2];
#pragma unroll
    for (int mi = 0; mi < 2; ++mi) {
      int r = w * 32 + mi * 16 + lr;
      ah[mi] = *(const short8v*)&sXh[r * 40 + quad * 8];
      al[mi] = *(const short8v*)&sXl[r * 40 + quad * 8];
    }
#pragma unroll
    for (int ni = 0; ni < 4; ++ni) {
      int n = ni * 16 + lr;
      short8v bh = *(const short8v*)&sWh[n * 136 + k0 + quad * 8];
      short8v bl = *(const short8v*)&sWl[n * 136 + k0 + quad * 8];
#pragma unroll
      for (int mi = 0; mi < 2; ++mi) {
        acc[mi][ni] = __builtin_amdgcn_mfma_f32_16x16x32_bf16(ah[mi], bh, acc[mi][ni], 0, 0, 0);
        acc[mi][ni] = __builtin_amdgcn_mfma_f32_16x16x32_bf16(ah[mi], bl, acc[mi][ni], 0, 0, 0);
        acc[mi][ni] = __builtin_amdgcn_mfma_f32_16x16x32_bf16(al[mi], bh, acc[mi][ni], 0, 0, 0);
      }
    }
  }

#pragma unroll
  for (int mi = 0; mi < 2; ++mi) {
#pragma unroll
    for (int r = 0; r < 4; ++r) {
      int grow = row0 + w * 32 + mi * 16 + quad * 4 + r;
      if (grow < NN) {
        float d = dinv[grow];
#pragma unroll
        for (int ni = 0; ni < 4; ++ni)
          Hs[(size_t)grow * CH + col0 + ni * 16 + lr] = f2bf(d * acc[mi][ni][r]);
      }
    }
  }
}

// out[i] = relu(dinv[i]*(Hs[i] + sum Hs[csr[e]]) + b). One wave per node.
// Uniform masked 8-groups, software-pipelined prefetch: 16 gathers in flight,
// no serial tail (clamped dup indices are L1-hot; invalid slots zeroed).
__global__ __launch_bounds__(256) void k_aggregate(
    const unsigned* __restrict__ H, const int* __restrict__ rows,
    const int* __restrict__ csr, const float* __restrict__ dinv,
    const float* __restrict__ bias, float* __restrict__ out) {
  int node = blockIdx.x * 4 + (threadIdx.x >> 6);
  int lane = threadIdx.x & 63;
  if (node >= NN) return;
  float bx = bias[2 * lane], by = bias[2 * lane + 1];
  unsigned sv = H[(size_t)node * 64 + lane];  // self-loop term
  float ax = bflo(sv), ay = bfhi(sv);
  int e0 = rows[node], e1 = rows[node + 1];
  int deg = e1 - e0;
  if (deg > 0) {
    int elast = e1 - 1;
    unsigned va[8], vb[8];
#pragma unroll
    for (int k = 0; k < 8; ++k) {
      int ee = e0 + k;
      int j = csr[ee <= elast ? ee : elast];
      va[k] = H[(size_t)j * 64 + lane];
    }
    int ngroups = (deg + 7) >> 3;
    int base = e0;
    for (int g = 1; g < ngroups; ++g) {
      int nb = e0 + g * 8;
#pragma unroll
      for (int k = 0; k < 8; ++k) {
        int ee = nb + k;
        int j = csr[ee <= elast ? ee : elast];
        vb[k] = H[(size_t)j * 64 + lane];
      }
      // previous group is always full
#pragma unroll
      for (int k = 0; k < 8; ++k) { ax += bflo(va[k]); ay += bfhi(va[k]); }
#pragma unroll
      for (int k = 0; k < 8; ++k) va[k] = vb[k];
      base = nb;
    }
    int rem = e1 - base;  // 1..8
#pragma unroll
    for (int k = 0; k < 8; ++k) {
      unsigned v = (k < rem) ? va[k] : 0u;
      ax += bflo(v);
      ay += bfhi(v);
    }
  }
  float d = dinv[node];
  float2 o;
  o.x = fmaxf(fmaf(d, ax, bx), 0.f);
  o.y = fmaxf(fmaf(d, ay, by), 0.f);
  ((float2*)out)[(size_t)node * 64 + lane] = o;
}

// Fused per-graph pipeline: segmented mean pool -> MLP1 (relu) -> MLP2 -> out.
__global__ __launch_bounds__(256) void k_head(
    const float* __restrict__ A, const int* __restrict__ start,
    const float* __restrict__ W3, const float* __restrict__ b3,
    const float* __restrict__ W4, const float* __restrict__ b4,
    float* __restrict__ out) {
  __shared__ float pooled[128];
  __shared__ float part[128];
  __shared__ float g1[128];
  int g = blockIdx.x;
  int c = threadIdx.x & 127;
  int half = threadIdx.x >> 7;
  int s0 = start[g], s1 = start[g + 1];
  float sum = 0.f;
  for (int i = s0 + half; i < s1; i += 2)
    sum += A[(size_t)i * CH + c];
  if (half) part[c] = sum;
  __syncthreads();
  if (!half) {
    float n = fmaxf((float)(s1 - s0), 1.0f);
    pooled[c] = (sum + part[c]) / n;
  }
  __syncthreads();
  if (threadIdx.x < 128) {
    float acc = b3[c];
    for (int k = 0; k < 128; ++k) acc += pooled[k] * W3[k * CH + c];
    g1[c] = fmaxf(acc, 0.f);
  }
  __syncthreads();
  if (threadIdx.x < 64) {
    float acc = b4[threadIdx.x];
    for (int k = 0; k < 128; ++k) acc += g1[k] * W4[k * OC + threadIdx.x];
    out[(size_t)g * OC + threadIdx.x] = acc;
  }
}

extern "C" void kernel_launch(void* const* d_in, const int* in_sizes, int n_in,
                              void* d_out, int out_size, void* d_ws, size_t ws_size,
                              hipStream_t stream) {
  const float* X   = (const float*)d_in[0];
  const int* ei    = (const int*)d_in[1];
  const int* batch = (const int*)d_in[2];
  const float* W1  = (const float*)d_in[3];
  const float* b1  = (const float*)d_in[4];
  const float* W2  = (const float*)d_in[5];
  const float* b2  = (const float*)d_in[6];
  const float* W3  = (const float*)d_in[7];
  const float* b3  = (const float*)d_in[8];
  const float* W4  = (const float*)d_in[9];
  const float* b4  = (const float*)d_in[10];
  float* out = (float*)d_out;
  float* ws = (float*)d_ws;

  const int* src = ei;        // edge_index[0]
  const int* dst = ei + EE;   // edge_index[1]

  float* dinv = ws + O_DINV;
  int* rows   = (int*)(ws + O_ROWS);
  int* cnt    = (int*)(ws + O_CNT);
  int* part   = (int*)(ws + O_PART);
  int* offs   = (int*)(ws + O_OFFS);
  int* csr    = (int*)(ws + O_CSR);
  unsigned short* Hs = (unsigned short*)(ws + O_HS);
  unsigned* stg = (unsigned*)(ws + O_STG);
  unsigned short* wt1 = (unsigned short*)(ws + O_WT1);
  unsigned short* wt2 = (unsigned short*)(ws + O_WT2);
  float* A1   = ws + O_A1;
  int* start  = (int*)(ws + O_START);

  k_part<<<PBLK, 1024, 0, stream>>>(src, dst, cnt, stg);
  k_count<<<NCB, 1024, 0, stream>>>(stg, cnt, rows, part, dinv);
  k_scan_part<<<1, 128, 0, stream>>>(part, offs);
  k_scan_add<<<(NN + 255) / 256, 256, 0, stream>>>(rows, offs, batch, start);
  k_place<<<NCB, 1024, 0, stream>>>(stg, cnt, rows, csr);
  // after k_place the staging region is dead; wt1/wt2 overwrite its start
  k_wsplit<<<128, 256, 0, stream>>>(W1, W2, wt1, wt2);

  dim3 ggrid((NN + 127) / 128, 2);
  // layer 1
  k_gemm_mfma<<<ggrid, 256, 0, stream>>>(X, wt1, wt1 + 16384, dinv, Hs);
  k_aggregate<<<(NN + 3) / 4, 256, 0, stream>>>((const unsigned*)Hs, rows, csr, dinv, b1, A1);
  // layer 2
  k_gemm_mfma<<<ggrid, 256, 0, stream>>>(A1, wt2, wt2 + 16384, dinv, Hs);
  k_aggregate<<<(NN + 3) / 4, 256, 0, stream>>>((const unsigned*)Hs, rows, csr, dinv, b2, A1);

  k_head<<<NG, 256, 0, stream>>>(A1, start, W3, b3, W4, b4, out);
}